// Round 4
// baseline (1032.342 us; speedup 1.0000x reference)
//
#include <hip/hip_runtime.h>
#include <cmath>

#define LEAKY(v) ((v) > 0.f ? (v) : 0.2f*(v))

__device__ __forceinline__ float bf2f(unsigned short h){
  union { unsigned u; float f; } c; c.u = ((unsigned)h) << 16; return c.f;
}
__device__ __forceinline__ unsigned short f2bf(float f){
  union { float f; unsigned u; } c; c.f = f;
  unsigned u = c.u + 0x7FFFu + ((c.u >> 16) & 1u);
  return (unsigned short)(u >> 16);
}

// ---------------- CSR build ----------------

__global__ void deg_kernel(const int* __restrict__ dst, int* __restrict__ degi, int E){
  int e = blockIdx.x*256 + threadIdx.x;
  if (e < E) atomicAdd(&degi[dst[e]], 1);
}

__global__ void scan_kernel(const int* __restrict__ degi, int* __restrict__ row_off, int N){
  __shared__ int part[1024];
  int t = threadIdx.x;
  int chunk = (N + 1023) >> 10;
  int s0 = t*chunk, s1 = min(s0 + chunk, N);
  int sum = 0;
  for (int i = s0; i < s1; i++) sum += degi[i];
  part[t] = sum; __syncthreads();
  for (int off = 1; off < 1024; off <<= 1){
    int v = (t >= off) ? part[t - off] : 0;
    __syncthreads();
    part[t] += v;
    __syncthreads();
  }
  int run = (t == 0) ? 0 : part[t-1];
  for (int i = s0; i < s1; i++){ row_off[i] = run; run += degi[i]; }
  if (t == 1023) row_off[N] = run;
}

__global__ void scatter_kernel(const int* __restrict__ src, const int* __restrict__ dst,
                               const int* __restrict__ row_off, int* __restrict__ cursor,
                               int* __restrict__ csr_src, int E){
  int e = blockIdx.x*256 + threadIdx.x;
  if (e < E){
    int d = dst[e];
    int pos = row_off[d] + atomicAdd(&cursor[d], 1);
    csr_src[pos] = src[e];
  }
}

// ---------------- GEMM: O[N,M] = X[N,K] @ W[K,M]; 128x128 tile, 8x8 microtile ----------------
// BF16OUT: write bf16 (RNE) for gather arrays; else fp32.

template<bool BF16OUT>
__global__ __launch_bounds__(256) void gemm128(const float* __restrict__ X,
                                               const float* __restrict__ W,
                                               void* __restrict__ Ov,
                                               int N, int K, int M){
  __shared__ float Xs[32][132];   // [k][r]
  __shared__ float Ws[32][128];   // [k][c]
  int t = threadIdx.x;
  int n0 = blockIdx.x*128, c0 = blockIdx.y*128;
  int tx = t & 15, ty = t >> 4;
  float acc[8][8];
  #pragma unroll
  for (int i = 0; i < 8; i++)
    #pragma unroll
    for (int j = 0; j < 8; j++) acc[i][j] = 0.f;

  int k0 = 0;
  for (; k0 + 32 <= K; k0 += 32){
    #pragma unroll
    for (int i = 0; i < 16; i++){
      int idx = t + i*256;
      int r = idx >> 5, kk = idx & 31;
      int n = n0 + r;
      Xs[kk][r] = (n < N) ? X[(size_t)n*K + k0 + kk] : 0.f;
    }
    #pragma unroll
    for (int i = 0; i < 16; i++){
      int idx = t + i*256;
      int kk = idx >> 7, c = idx & 127;
      Ws[kk][c] = W[(size_t)(k0+kk)*M + c0 + c];
    }
    __syncthreads();
    #pragma unroll
    for (int kk = 0; kk < 32; kk++){
      float4 xa = *(const float4*)&Xs[kk][ty*8];
      float4 xb = *(const float4*)&Xs[kk][ty*8+4];
      float4 wa = *(const float4*)&Ws[kk][tx*8];
      float4 wb = *(const float4*)&Ws[kk][tx*8+4];
      float xv[8] = {xa.x,xa.y,xa.z,xa.w,xb.x,xb.y,xb.z,xb.w};
      float wv[8] = {wa.x,wa.y,wa.z,wa.w,wb.x,wb.y,wb.z,wb.w};
      #pragma unroll
      for (int i = 0; i < 8; i++)
        #pragma unroll
        for (int j = 0; j < 8; j++) acc[i][j] += xv[i]*wv[j];
    }
    __syncthreads();
  }
  int rem = K - k0;
  if (rem > 0){
    #pragma unroll
    for (int i = 0; i < 16; i++){
      int idx = t + i*256;
      int r = idx >> 5, kk = idx & 31;
      int n = n0 + r;
      Xs[kk][r] = (n < N && kk < rem) ? X[(size_t)n*K + k0 + kk] : 0.f;
    }
    #pragma unroll
    for (int i = 0; i < 16; i++){
      int idx = t + i*256;
      int kk = idx >> 7, c = idx & 127;
      Ws[kk][c] = (kk < rem) ? W[(size_t)(k0+kk)*M + c0 + c] : 0.f;
    }
    __syncthreads();
    for (int kk = 0; kk < rem; kk++){
      float4 xa = *(const float4*)&Xs[kk][ty*8];
      float4 xb = *(const float4*)&Xs[kk][ty*8+4];
      float4 wa = *(const float4*)&Ws[kk][tx*8];
      float4 wb = *(const float4*)&Ws[kk][tx*8+4];
      float xv[8] = {xa.x,xa.y,xa.z,xa.w,xb.x,xb.y,xb.z,xb.w};
      float wv[8] = {wa.x,wa.y,wa.z,wa.w,wb.x,wb.y,wb.z,wb.w};
      #pragma unroll
      for (int i = 0; i < 8; i++)
        #pragma unroll
        for (int j = 0; j < 8; j++) acc[i][j] += xv[i]*wv[j];
    }
    __syncthreads();
  }

  #pragma unroll
  for (int i = 0; i < 8; i++){
    int n = n0 + ty*8 + i;
    if (n >= N) continue;
    if (BF16OUT){
      unsigned short* O = (unsigned short*)Ov;
      ushort4 u0, u1;
      u0.x = f2bf(acc[i][0]); u0.y = f2bf(acc[i][1]); u0.z = f2bf(acc[i][2]); u0.w = f2bf(acc[i][3]);
      u1.x = f2bf(acc[i][4]); u1.y = f2bf(acc[i][5]); u1.z = f2bf(acc[i][6]); u1.w = f2bf(acc[i][7]);
      ushort4* p = (ushort4*)&O[(size_t)n*M + c0 + tx*8];
      p[0] = u0; p[1] = u1;
    } else {
      float* O = (float*)Ov;
      float4 v0, v1;
      v0.x = acc[i][0]; v0.y = acc[i][1]; v0.z = acc[i][2]; v0.w = acc[i][3];
      v1.x = acc[i][4]; v1.y = acc[i][5]; v1.z = acc[i][6]; v1.w = acc[i][7];
      float4* p = (float4*)&O[(size_t)n*M + c0 + tx*8];
      p[0] = v0; p[1] = v1;
    }
  }
}

// ---------------- fused GATv2 edge phase: wave-per-node, barrier-free, bf16 xl ----------------
// H=2, CH=256: lane holds channels 4*lane..4*lane+3; lanes 0-31 = head 0, 32-63 = head 1.
// out may alias xr: wave n reads only xr row n, writes only out row n.

__global__ __launch_bounds__(256) void fused_gat_wave2(
    const int* __restrict__ row_off, const int* __restrict__ csr_src,
    const unsigned short* __restrict__ xlbf, const float* __restrict__ xr,
    const float* __restrict__ att, const float* __restrict__ bias,
    float* __restrict__ out, int N)
{
  int n = blockIdx.x*4 + (threadIdx.x >> 6);
  if (n >= N) return;
  int lane = threadIdx.x & 63;
  int r0 = row_off[n], r1 = row_off[n+1];
  const ushort4* xl4 = (const ushort4*)xlbf;
  float4 xrv = ((const float4*)xr)[(size_t)n*64 + lane];
  float4 attv = ((const float4*)att)[lane];
  float m = -INFINITY, l = 0.f;
  float4 acc = {0.f,0.f,0.f,0.f};

  if (r1 > r0){
    int s = csr_src[r0];
    ushort4 xu = xl4[(size_t)s*64 + lane];
    for (int p = r0; p < r1; p++){
      int s2 = csr_src[(p+1 < r1) ? p+1 : p];
      ushort4 xn = xl4[(size_t)s2*64 + lane];
      float x0 = bf2f(xu.x), x1 = bf2f(xu.y), x2 = bf2f(xu.z), x3 = bf2f(xu.w);
      float e0 = x0 + xrv.x; e0 = LEAKY(e0);
      float e1 = x1 + xrv.y; e1 = LEAKY(e1);
      float e2 = x2 + xrv.z; e2 = LEAKY(e2);
      float e3 = x3 + xrv.w; e3 = LEAKY(e3);
      float dot = e0*attv.x + e1*attv.y + e2*attv.z + e3*attv.w;
      dot += __shfl_xor(dot, 16);
      dot += __shfl_xor(dot, 8);
      dot += __shfl_xor(dot, 4);
      dot += __shfl_xor(dot, 2);
      dot += __shfl_xor(dot, 1);   // per-32-half sum -> per-head logit
      float nm = fmaxf(m, dot);
      float sc = __expf(m - nm);   // 0 on first edge (m = -inf)
      float w  = __expf(dot - nm);
      l = l*sc + w;
      acc.x = acc.x*sc + w*x0;
      acc.y = acc.y*sc + w*x1;
      acc.z = acc.z*sc + w*x2;
      acc.w = acc.w*sc + w*x3;
      m = nm;
      xu = xn;
    }
  }
  float4 bv = ((const float4*)bias)[lane];
  float4 res = bv;
  if (r1 > r0){
    float inv = 1.f / (l * (float)(r1 - r0));
    res.x += acc.x*inv; res.y += acc.y*inv; res.z += acc.z*inv; res.w += acc.w*inv;
  }
  ((float4*)out)[(size_t)n*64 + lane] = res;
}

// H=1, CH=128: lane holds channels 2*lane..2*lane+1; reduce over all 64 lanes.
__global__ __launch_bounds__(256) void fused_gat_wave1(
    const int* __restrict__ row_off, const int* __restrict__ csr_src,
    const unsigned short* __restrict__ xlbf, const float* __restrict__ xr,
    const float* __restrict__ att, const float* __restrict__ bias,
    float* __restrict__ out, int N)
{
  int n = blockIdx.x*4 + (threadIdx.x >> 6);
  if (n >= N) return;
  int lane = threadIdx.x & 63;
  int r0 = row_off[n], r1 = row_off[n+1];
  const ushort2* xl2 = (const ushort2*)xlbf;
  float2 xrv = ((const float2*)xr)[(size_t)n*64 + lane];
  float2 attv = ((const float2*)att)[lane];
  float m = -INFINITY, l = 0.f;
  float2 acc = {0.f,0.f};

  if (r1 > r0){
    int s = csr_src[r0];
    ushort2 xu = xl2[(size_t)s*64 + lane];
    for (int p = r0; p < r1; p++){
      int s2 = csr_src[(p+1 < r1) ? p+1 : p];
      ushort2 xn = xl2[(size_t)s2*64 + lane];
      float x0 = bf2f(xu.x), x1 = bf2f(xu.y);
      float e0 = x0 + xrv.x; e0 = LEAKY(e0);
      float e1 = x1 + xrv.y; e1 = LEAKY(e1);
      float dot = e0*attv.x + e1*attv.y;
      dot += __shfl_xor(dot, 32);
      dot += __shfl_xor(dot, 16);
      dot += __shfl_xor(dot, 8);
      dot += __shfl_xor(dot, 4);
      dot += __shfl_xor(dot, 2);
      dot += __shfl_xor(dot, 1);
      float nm = fmaxf(m, dot);
      float sc = __expf(m - nm);
      float w  = __expf(dot - nm);
      l = l*sc + w;
      acc.x = acc.x*sc + w*x0;
      acc.y = acc.y*sc + w*x1;
      m = nm;
      xu = xn;
    }
  }
  float2 bv = ((const float2*)bias)[lane];
  float2 res = bv;
  if (r1 > r0){
    float inv = 1.f / (l * (float)(r1 - r0));
    res.x += acc.x*inv; res.y += acc.y*inv;
  }
  ((float2*)out)[(size_t)n*64 + lane] = res;
}

// ---------------- layer 3 (C=1) ----------------

__global__ __launch_bounds__(256) void gemm3_kernel(const float* __restrict__ h2,
                                                    const float* __restrict__ W3l,
                                                    const float* __restrict__ W3r,
                                                    float* __restrict__ xl3,
                                                    float* __restrict__ xr3, int N){
  int n = blockIdx.x*4 + (threadIdx.x >> 6);
  int lane = threadIdx.x & 63;
  if (n >= N) return;
  float v1 = h2[(size_t)n*128 + lane];
  float v2 = h2[(size_t)n*128 + 64 + lane];
  float al = v1*W3l[lane] + v2*W3l[64 + lane];
  float ar = v1*W3r[lane] + v2*W3r[64 + lane];
  #pragma unroll
  for (int off = 32; off > 0; off >>= 1){
    al += __shfl_down(al, off);
    ar += __shfl_down(ar, off);
  }
  if (lane == 0){ xl3[n] = al; xr3[n] = ar; }
}

// fused logits + online softmax + mean for C=1 (one thread per node, single pass)
__global__ void aggr3_kernel(const int* __restrict__ row_off, const int* __restrict__ csr_src,
                             const float* __restrict__ xl3, const float* __restrict__ xr3,
                             const float* __restrict__ a3, const float* __restrict__ b3,
                             float* __restrict__ h3, int N){
  int n = blockIdx.x*256 + threadIdx.x;
  if (n >= N) return;
  int r0 = row_off[n], r1 = row_off[n+1];
  int deg = r1 - r0;
  float b = b3[0];
  if (deg == 0){ h3[n] = b; return; }
  float xr = xr3[n];
  float aa = a3[0];
  float m = -INFINITY, den = 0.f, s = 0.f;
  for (int p = r0; p < r1; p++){
    float xlv = xl3[csr_src[p]];
    float v = xlv + xr;
    v = LEAKY(v) * aa;
    if (v > m){
      float sc = __expf(m - v);
      den *= sc; s *= sc; m = v;
    }
    float a = __expf(v - m);
    den += a;
    s += a * xlv;
  }
  h3[n] = s/den/(float)deg + b;
}

__global__ void out_kernel(const float* __restrict__ h3, const float* __restrict__ y,
                           const int* __restrict__ tidx, float* __restrict__ out, int T){
  int i = blockIdx.x*256 + threadIdx.x;
  if (i >= T) return;
  int n = tidx[i];
  out[i] = 1.f/(1.f + __expf(-h3[n]));
  out[T + i] = y[n];
}

// ---------------- launch ----------------

extern "C" void kernel_launch(void* const* d_in, const int* in_sizes, int n_in,
                              void* d_out, int out_size, void* d_ws, size_t ws_size,
                              hipStream_t stream){
  const float* x    = (const float*)d_in[0];
  const int*   ei   = (const int*)d_in[1];
  const float* y    = (const float*)d_in[2];
  const int*   tidx = (const int*)d_in[3];
  const float* W1l  = (const float*)d_in[4];
  const float* W1r  = (const float*)d_in[5];
  const float* a1   = (const float*)d_in[6];
  const float* b1   = (const float*)d_in[7];
  const float* W2l  = (const float*)d_in[8];
  const float* W2r  = (const float*)d_in[9];
  const float* a2   = (const float*)d_in[10];
  const float* b2   = (const float*)d_in[11];
  const float* W3l  = (const float*)d_in[12];
  const float* W3r  = (const float*)d_in[13];
  const float* a3   = (const float*)d_in[14];
  const float* b3   = (const float*)d_in[15];

  int N = in_sizes[2];        // 50000 nodes
  int E = in_sizes[1] / 2;    // 800000 edges
  int T = in_sizes[3];        // 40000 train indices
  const int* src = ei;
  const int* dst = ei + E;

  char* w = (char*)d_ws;
  size_t off = 0;
  auto take = [&](size_t bytes) -> char* {
    char* p = w + off;
    off = (off + bytes + 255) & ~(size_t)255;
    return p;
  };
  int*   row_off = (int*)  take((size_t)(N+1)*4);
  int*   degi    = (int*)  take((size_t)N*4);
  int*   cursor  = (int*)  take((size_t)N*4);
  int*   csr_src = (int*)  take((size_t)E*4);
  float* A       = (float*)take((size_t)N*256*4);
  float* B       = (float*)take((size_t)N*256*4);

  // ---- CSR build (graph shared by all 3 layers) ----
  hipMemsetAsync(degi, 0, (size_t)N*4, stream);
  hipMemsetAsync(cursor, 0, (size_t)N*4, stream);
  deg_kernel<<<(E+255)/256, 256, 0, stream>>>(dst, degi, E);
  scan_kernel<<<1, 1024, 0, stream>>>(degi, row_off, N);
  scatter_kernel<<<(E+255)/256, 256, 0, stream>>>(src, dst, row_off, cursor, csr_src, E);

  // ---- layer 1: 129 -> 256 (H=2, C=128) ----
  unsigned short* xl1bf = (unsigned short*)A;            // N*256 ushort (= A[0 : N*128) floats)
  float*          xr1   = B;                             // N*256 f32
  gemm128<true ><<<dim3((N+127)/128, 2), 256, 0, stream>>>(x, W1l, xl1bf, N, 129, 256);
  gemm128<false><<<dim3((N+127)/128, 2), 256, 0, stream>>>(x, W1r, xr1,   N, 129, 256);
  fused_gat_wave2<<<(N+3)/4, 256, 0, stream>>>(row_off, csr_src, xl1bf, xr1, a1, b1, B, N);
  float* h1 = B;

  // ---- layer 2: 256 -> 128 (H=1, C=128) ----
  unsigned short* xl2bf = (unsigned short*)A;            // N*128 ushort (overwrites dead xl1bf)
  float*          xr2   = A + (size_t)N*128;             // N*128 f32
  gemm128<true ><<<dim3((N+127)/128, 1), 256, 0, stream>>>(h1, W2l, xl2bf, N, 256, 128);
  gemm128<false><<<dim3((N+127)/128, 1), 256, 0, stream>>>(h1, W2r, xr2,   N, 256, 128);
  fused_gat_wave1<<<(N+3)/4, 256, 0, stream>>>(row_off, csr_src, xl2bf, xr2, a2, b2, xr2, N);
  float* h2 = xr2;

  // ---- layer 3: 128 -> 1 (H=1, C=1) ----
  float* xl3 = B;
  float* xr3 = B + N;
  float* h3  = B + 2*(size_t)N;
  gemm3_kernel<<<(N+3)/4, 256, 0, stream>>>(h2, W3l, W3r, xl3, xr3, N);
  aggr3_kernel<<<(N+255)/256, 256, 0, stream>>>(row_off, csr_src, xl3, xr3, a3, b3, h3, N);

  // ---- output: (sigmoid(h3)[tidx], y[tidx]) ----
  out_kernel<<<(T+255)/256, 256, 0, stream>>>(h3, y, tidx, (float*)d_out, T);
}

// Round 5
// 873.848 us; speedup vs baseline: 1.1814x; 1.1814x over previous
//
#include <hip/hip_runtime.h>
#include <cmath>

#define LEAKY(v) ((v) > 0.f ? (v) : 0.2f*(v))

__device__ __forceinline__ float bf2f(unsigned short h){
  union { unsigned u; float f; } c; c.u = ((unsigned)h) << 16; return c.f;
}
__device__ __forceinline__ unsigned short f2bf(float f){
  union { float f; unsigned u; } c; c.f = f;
  unsigned u = c.u + 0x7FFFu + ((c.u >> 16) & 1u);
  return (unsigned short)(u >> 16);
}

typedef __attribute__((ext_vector_type(8))) short bfrag;   // 8 bf16 = 4 VGPR
typedef __attribute__((ext_vector_type(4))) float ffrag;   // 4 f32 acc

// ---------------- CSR build ----------------

__global__ void deg_kernel(const int* __restrict__ dst, int* __restrict__ degi, int E){
  int e = blockIdx.x*256 + threadIdx.x;
  if (e < E) atomicAdd(&degi[dst[e]], 1);
}

__global__ void scan_kernel(const int* __restrict__ degi, int* __restrict__ row_off, int N){
  __shared__ int part[1024];
  int t = threadIdx.x;
  int chunk = (N + 1023) >> 10;
  int s0 = t*chunk, s1 = min(s0 + chunk, N);
  int sum = 0;
  for (int i = s0; i < s1; i++) sum += degi[i];
  part[t] = sum; __syncthreads();
  for (int off = 1; off < 1024; off <<= 1){
    int v = (t >= off) ? part[t - off] : 0;
    __syncthreads();
    part[t] += v;
    __syncthreads();
  }
  int run = (t == 0) ? 0 : part[t-1];
  for (int i = s0; i < s1; i++){ row_off[i] = run; run += degi[i]; }
  if (t == 1023) row_off[N] = run;
}

__global__ void scatter_kernel(const int* __restrict__ src, const int* __restrict__ dst,
                               const int* __restrict__ row_off, int* __restrict__ cursor,
                               int* __restrict__ csr_src, int E){
  int e = blockIdx.x*256 + threadIdx.x;
  if (e < E){
    int d = dst[e];
    int pos = row_off[d] + atomicAdd(&cursor[d], 1);
    csr_src[pos] = src[e];
  }
}

// ---------------- MFMA bf16 GEMM: O[N,M] = X[N,K] @ W[K,M] ----------------
// fp32 inputs converted to bf16 during LDS staging; fp32 accumulate.
// 64x128 tile, 4 waves (2x2), each wave 32x64 = 2x4 mfma 16x16x32 tiles.
// LDS layouts sized for single ds_read_b128 fragments:
//   Xs[m][k] rows of 40 halves (80 B, 16B-aligned) -> A frag: m=lane&15, k=quad*8+j
//   Ws[n][k] transposed, rows of 40 halves        -> B frag: k=quad*8+j, n=lane&15
// C/D layout (verified): col=lane&15, row=quad*4+reg.

template<bool BF16OUT>
__global__ __launch_bounds__(256) void gemm_mfma(const float* __restrict__ X,
                                                 const float* __restrict__ W,
                                                 void* __restrict__ Ov,
                                                 int N, int K, int M){
  __shared__ unsigned short Xs[64*40];
  __shared__ unsigned short Ws[128*40];
  int t = threadIdx.x;
  int n0 = blockIdx.x*64, c0 = blockIdx.y*128;
  int wv = t >> 6, lane = t & 63;
  int wr = wv >> 1, wc = wv & 1;          // wave's 32-row, 64-col quadrant
  int m16 = lane & 15, quad = lane >> 4;

  ffrag acc[2][4];
  #pragma unroll
  for (int i = 0; i < 2; i++)
    #pragma unroll
    for (int j = 0; j < 4; j++) acc[i][j] = (ffrag){0.f,0.f,0.f,0.f};

  for (int k0 = 0; k0 < K; k0 += 32){
    // stage X tile 64 rows x 32 k (coalesced 128B per row-pair), cvt to bf16
    #pragma unroll
    for (int it = 0; it < 8; it++){
      int idx = t + it*256;
      int r = idx >> 5, kk = idx & 31;
      int n = n0 + r, k = k0 + kk;
      float v = (n < N && k < K) ? X[(size_t)n*K + k] : 0.f;
      Xs[r*40 + kk] = f2bf(v);
    }
    // stage W tile 32 k x 128 cols, transposed store Ws[c][kk]
    #pragma unroll
    for (int it = 0; it < 16; it++){
      int idx = t + it*256;
      int kk = idx >> 7, c = idx & 127;
      int k = k0 + kk;
      float v = (k < K) ? W[(size_t)k*M + c0 + c] : 0.f;
      Ws[c*40 + kk] = f2bf(v);
    }
    __syncthreads();
    bfrag a[2], b[4];
    #pragma unroll
    for (int i = 0; i < 2; i++){
      int m = wr*32 + i*16 + m16;
      a[i] = *(const bfrag*)&Xs[m*40 + quad*8];
    }
    #pragma unroll
    for (int j = 0; j < 4; j++){
      int c = wc*64 + j*16 + m16;
      b[j] = *(const bfrag*)&Ws[c*40 + quad*8];
    }
    #pragma unroll
    for (int i = 0; i < 2; i++)
      #pragma unroll
      for (int j = 0; j < 4; j++)
        acc[i][j] = __builtin_amdgcn_mfma_f32_16x16x32_bf16(a[i], b[j], acc[i][j], 0, 0, 0);
    __syncthreads();
  }

  // epilogue: row = n0 + wr*32 + i*16 + quad*4 + reg; col = c0 + wc*64 + j*16 + m16
  #pragma unroll
  for (int i = 0; i < 2; i++){
    #pragma unroll
    for (int reg = 0; reg < 4; reg++){
      int rr = n0 + wr*32 + i*16 + quad*4 + reg;
      if (rr >= N) continue;
      #pragma unroll
      for (int j = 0; j < 4; j++){
        int cc = c0 + wc*64 + j*16 + m16;
        float v = acc[i][j][reg];
        if (BF16OUT) ((unsigned short*)Ov)[(size_t)rr*M + cc] = f2bf(v);
        else         ((float*)Ov)[(size_t)rr*M + cc] = v;
      }
    }
  }
}

// ---------------- fused GATv2 edge phase: wave-per-node, barrier-free, bf16 xl ----------------

__global__ __launch_bounds__(256) void fused_gat_wave2(
    const int* __restrict__ row_off, const int* __restrict__ csr_src,
    const unsigned short* __restrict__ xlbf, const float* __restrict__ xr,
    const float* __restrict__ att, const float* __restrict__ bias,
    float* __restrict__ out, int N)
{
  int n = blockIdx.x*4 + (threadIdx.x >> 6);
  if (n >= N) return;
  int lane = threadIdx.x & 63;
  int r0 = row_off[n], r1 = row_off[n+1];
  const ushort4* xl4 = (const ushort4*)xlbf;
  float4 xrv = ((const float4*)xr)[(size_t)n*64 + lane];
  float4 attv = ((const float4*)att)[lane];
  float m = -INFINITY, l = 0.f;
  float4 acc = {0.f,0.f,0.f,0.f};

  if (r1 > r0){
    int s = csr_src[r0];
    ushort4 xu = xl4[(size_t)s*64 + lane];
    for (int p = r0; p < r1; p++){
      int s2 = csr_src[(p+1 < r1) ? p+1 : p];
      ushort4 xn = xl4[(size_t)s2*64 + lane];
      float x0 = bf2f(xu.x), x1 = bf2f(xu.y), x2 = bf2f(xu.z), x3 = bf2f(xu.w);
      float e0 = x0 + xrv.x; e0 = LEAKY(e0);
      float e1 = x1 + xrv.y; e1 = LEAKY(e1);
      float e2 = x2 + xrv.z; e2 = LEAKY(e2);
      float e3 = x3 + xrv.w; e3 = LEAKY(e3);
      float dot = e0*attv.x + e1*attv.y + e2*attv.z + e3*attv.w;
      dot += __shfl_xor(dot, 16);
      dot += __shfl_xor(dot, 8);
      dot += __shfl_xor(dot, 4);
      dot += __shfl_xor(dot, 2);
      dot += __shfl_xor(dot, 1);   // per-32-half sum -> per-head logit
      float nm = fmaxf(m, dot);
      float sc = __expf(m - nm);   // 0 on first edge (m = -inf)
      float w  = __expf(dot - nm);
      l = l*sc + w;
      acc.x = acc.x*sc + w*x0;
      acc.y = acc.y*sc + w*x1;
      acc.z = acc.z*sc + w*x2;
      acc.w = acc.w*sc + w*x3;
      m = nm;
      xu = xn;
    }
  }
  float4 bv = ((const float4*)bias)[lane];
  float4 res = bv;
  if (r1 > r0){
    float inv = 1.f / (l * (float)(r1 - r0));
    res.x += acc.x*inv; res.y += acc.y*inv; res.z += acc.z*inv; res.w += acc.w*inv;
  }
  ((float4*)out)[(size_t)n*64 + lane] = res;
}

__global__ __launch_bounds__(256) void fused_gat_wave1(
    const int* __restrict__ row_off, const int* __restrict__ csr_src,
    const unsigned short* __restrict__ xlbf, const float* __restrict__ xr,
    const float* __restrict__ att, const float* __restrict__ bias,
    float* __restrict__ out, int N)
{
  int n = blockIdx.x*4 + (threadIdx.x >> 6);
  if (n >= N) return;
  int lane = threadIdx.x & 63;
  int r0 = row_off[n], r1 = row_off[n+1];
  const ushort2* xl2 = (const ushort2*)xlbf;
  float2 xrv = ((const float2*)xr)[(size_t)n*64 + lane];
  float2 attv = ((const float2*)att)[lane];
  float m = -INFINITY, l = 0.f;
  float2 acc = {0.f,0.f};

  if (r1 > r0){
    int s = csr_src[r0];
    ushort2 xu = xl2[(size_t)s*64 + lane];
    for (int p = r0; p < r1; p++){
      int s2 = csr_src[(p+1 < r1) ? p+1 : p];
      ushort2 xn = xl2[(size_t)s2*64 + lane];
      float x0 = bf2f(xu.x), x1 = bf2f(xu.y);
      float e0 = x0 + xrv.x; e0 = LEAKY(e0);
      float e1 = x1 + xrv.y; e1 = LEAKY(e1);
      float dot = e0*attv.x + e1*attv.y;
      dot += __shfl_xor(dot, 32);
      dot += __shfl_xor(dot, 16);
      dot += __shfl_xor(dot, 8);
      dot += __shfl_xor(dot, 4);
      dot += __shfl_xor(dot, 2);
      dot += __shfl_xor(dot, 1);
      float nm = fmaxf(m, dot);
      float sc = __expf(m - nm);
      float w  = __expf(dot - nm);
      l = l*sc + w;
      acc.x = acc.x*sc + w*x0;
      acc.y = acc.y*sc + w*x1;
      m = nm;
      xu = xn;
    }
  }
  float2 bv = ((const float2*)bias)[lane];
  float2 res = bv;
  if (r1 > r0){
    float inv = 1.f / (l * (float)(r1 - r0));
    res.x += acc.x*inv; res.y += acc.y*inv;
  }
  ((float2*)out)[(size_t)n*64 + lane] = res;
}

// ---------------- layer 3 (C=1) ----------------

__global__ __launch_bounds__(256) void gemm3_kernel(const float* __restrict__ h2,
                                                    const float* __restrict__ W3l,
                                                    const float* __restrict__ W3r,
                                                    float* __restrict__ xl3,
                                                    float* __restrict__ xr3, int N){
  int n = blockIdx.x*4 + (threadIdx.x >> 6);
  int lane = threadIdx.x & 63;
  if (n >= N) return;
  float v1 = h2[(size_t)n*128 + lane];
  float v2 = h2[(size_t)n*128 + 64 + lane];
  float al = v1*W3l[lane] + v2*W3l[64 + lane];
  float ar = v1*W3r[lane] + v2*W3r[64 + lane];
  #pragma unroll
  for (int off = 32; off > 0; off >>= 1){
    al += __shfl_down(al, off);
    ar += __shfl_down(ar, off);
  }
  if (lane == 0){ xl3[n] = al; xr3[n] = ar; }
}

__global__ void aggr3_kernel(const int* __restrict__ row_off, const int* __restrict__ csr_src,
                             const float* __restrict__ xl3, const float* __restrict__ xr3,
                             const float* __restrict__ a3, const float* __restrict__ b3,
                             float* __restrict__ h3, int N){
  int n = blockIdx.x*256 + threadIdx.x;
  if (n >= N) return;
  int r0 = row_off[n], r1 = row_off[n+1];
  int deg = r1 - r0;
  float b = b3[0];
  if (deg == 0){ h3[n] = b; return; }
  float xr = xr3[n];
  float aa = a3[0];
  float m = -INFINITY, den = 0.f, s = 0.f;
  for (int p = r0; p < r1; p++){
    float xlv = xl3[csr_src[p]];
    float v = xlv + xr;
    v = LEAKY(v) * aa;
    if (v > m){
      float sc = __expf(m - v);
      den *= sc; s *= sc; m = v;
    }
    float a = __expf(v - m);
    den += a;
    s += a * xlv;
  }
  h3[n] = s/den/(float)deg + b;
}

__global__ void out_kernel(const float* __restrict__ h3, const float* __restrict__ y,
                           const int* __restrict__ tidx, float* __restrict__ out, int T){
  int i = blockIdx.x*256 + threadIdx.x;
  if (i >= T) return;
  int n = tidx[i];
  out[i] = 1.f/(1.f + __expf(-h3[n]));
  out[T + i] = y[n];
}

// ---------------- launch ----------------

extern "C" void kernel_launch(void* const* d_in, const int* in_sizes, int n_in,
                              void* d_out, int out_size, void* d_ws, size_t ws_size,
                              hipStream_t stream){
  const float* x    = (const float*)d_in[0];
  const int*   ei   = (const int*)d_in[1];
  const float* y    = (const float*)d_in[2];
  const int*   tidx = (const int*)d_in[3];
  const float* W1l  = (const float*)d_in[4];
  const float* W1r  = (const float*)d_in[5];
  const float* a1   = (const float*)d_in[6];
  const float* b1   = (const float*)d_in[7];
  const float* W2l  = (const float*)d_in[8];
  const float* W2r  = (const float*)d_in[9];
  const float* a2   = (const float*)d_in[10];
  const float* b2   = (const float*)d_in[11];
  const float* W3l  = (const float*)d_in[12];
  const float* W3r  = (const float*)d_in[13];
  const float* a3   = (const float*)d_in[14];
  const float* b3   = (const float*)d_in[15];

  int N = in_sizes[2];        // 50000 nodes
  int E = in_sizes[1] / 2;    // 800000 edges
  int T = in_sizes[3];        // 40000 train indices
  const int* src = ei;
  const int* dst = ei + E;

  char* w = (char*)d_ws;
  size_t off = 0;
  auto take = [&](size_t bytes) -> char* {
    char* p = w + off;
    off = (off + bytes + 255) & ~(size_t)255;
    return p;
  };
  int*   row_off = (int*)  take((size_t)(N+1)*4);
  int*   degi    = (int*)  take((size_t)N*4);
  int*   cursor  = (int*)  take((size_t)N*4);
  int*   csr_src = (int*)  take((size_t)E*4);
  float* A       = (float*)take((size_t)N*256*4);
  float* B       = (float*)take((size_t)N*256*4);

  // ---- CSR build (graph shared by all 3 layers) ----
  hipMemsetAsync(degi, 0, (size_t)N*4, stream);
  hipMemsetAsync(cursor, 0, (size_t)N*4, stream);
  deg_kernel<<<(E+255)/256, 256, 0, stream>>>(dst, degi, E);
  scan_kernel<<<1, 1024, 0, stream>>>(degi, row_off, N);
  scatter_kernel<<<(E+255)/256, 256, 0, stream>>>(src, dst, row_off, cursor, csr_src, E);

  // ---- layer 1: 129 -> 256 (H=2, C=128) ----
  unsigned short* xl1bf = (unsigned short*)A;            // N*256 bf16 in region A
  float*          xr1   = B;                             // N*256 f32
  gemm_mfma<true ><<<dim3((N+63)/64, 2), 256, 0, stream>>>(x, W1l, xl1bf, N, 129, 256);
  gemm_mfma<false><<<dim3((N+63)/64, 2), 256, 0, stream>>>(x, W1r, xr1,   N, 129, 256);
  fused_gat_wave2<<<(N+3)/4, 256, 0, stream>>>(row_off, csr_src, xl1bf, xr1, a1, b1, B, N);
  float* h1 = B;

  // ---- layer 2: 256 -> 128 (H=1, C=128) ----
  unsigned short* xl2bf = (unsigned short*)A;            // N*128 bf16 (overwrites dead xl1bf)
  float*          xr2   = A + (size_t)N*128;             // N*128 f32
  gemm_mfma<true ><<<dim3((N+63)/64, 1), 256, 0, stream>>>(h1, W2l, xl2bf, N, 256, 128);
  gemm_mfma<false><<<dim3((N+63)/64, 1), 256, 0, stream>>>(h1, W2r, xr2,   N, 256, 128);
  fused_gat_wave1<<<(N+3)/4, 256, 0, stream>>>(row_off, csr_src, xl2bf, xr2, a2, b2, xr2, N);
  float* h2 = xr2;

  // ---- layer 3: 128 -> 1 (H=1, C=1) ----
  float* xl3 = B;
  float* xr3 = B + N;
  float* h3  = B + 2*(size_t)N;
  gemm3_kernel<<<(N+3)/4, 256, 0, stream>>>(h2, W3l, W3r, xl3, xr3, N);
  aggr3_kernel<<<(N+255)/256, 256, 0, stream>>>(row_off, csr_src, xl3, xr3, a3, b3, h3, N);

  // ---- output: (sigmoid(h3)[tidx], y[tidx]) ----
  out_kernel<<<(T+255)/256, 256, 0, stream>>>(h3, y, tidx, (float*)d_out, T);
}

// Round 6
// 561.355 us; speedup vs baseline: 1.8390x; 1.5567x over previous
//
#include <hip/hip_runtime.h>
#include <cmath>

#define LEAKY(v) ((v) > 0.f ? (v) : 0.2f*(v))

__device__ __forceinline__ float bf2f(unsigned short h){
  union { unsigned u; float f; } c; c.u = ((unsigned)h) << 16; return c.f;
}
__device__ __forceinline__ unsigned short f2bf(float f){
  union { float f; unsigned u; } c; c.f = f;
  unsigned u = c.u + 0x7FFFu + ((c.u >> 16) & 1u);
  return (unsigned short)(u >> 16);
}

typedef __attribute__((ext_vector_type(8))) short bfrag;   // 8 bf16 = 4 VGPR
typedef __attribute__((ext_vector_type(4))) float ffrag;   // 4 f32 acc

// ---------------- CSR build ----------------

__global__ void deg_kernel(const int* __restrict__ dst, int* __restrict__ degi, int E){
  int e = blockIdx.x*256 + threadIdx.x;
  if (e < E) atomicAdd(&degi[dst[e]], 1);
}

__global__ void scan_kernel(const int* __restrict__ degi, int* __restrict__ row_off, int N){
  __shared__ int part[1024];
  int t = threadIdx.x;
  int chunk = (N + 1023) >> 10;
  int s0 = t*chunk, s1 = min(s0 + chunk, N);
  int sum = 0;
  for (int i = s0; i < s1; i++) sum += degi[i];
  part[t] = sum; __syncthreads();
  for (int off = 1; off < 1024; off <<= 1){
    int v = (t >= off) ? part[t - off] : 0;
    __syncthreads();
    part[t] += v;
    __syncthreads();
  }
  int run = (t == 0) ? 0 : part[t-1];
  for (int i = s0; i < s1; i++){ row_off[i] = run; run += degi[i]; }
  if (t == 1023) row_off[N] = run;
}

__global__ void scatter_kernel(const int* __restrict__ src, const int* __restrict__ dst,
                               const int* __restrict__ row_off, int* __restrict__ cursor,
                               int* __restrict__ csr_src, int E){
  int e = blockIdx.x*256 + threadIdx.x;
  if (e < E){
    int d = dst[e];
    int pos = row_off[d] + atomicAdd(&cursor[d], 1);
    csr_src[pos] = src[e];
  }
}

// ---------------- precision-prep kernels ----------------

// fp32 [N,K] -> bf16 [N,Kpad] zero-padded
__global__ void cvt_pad_kernel(const float* __restrict__ in, unsigned short* __restrict__ out,
                               int N, int K, int Kpad){
  int idx = blockIdx.x*256 + threadIdx.x;
  if (idx >= N*Kpad) return;
  int n = idx / Kpad, k = idx - n*Kpad;
  out[idx] = (k < K) ? f2bf(in[(size_t)n*K + k]) : (unsigned short)0;
}

// fp32 -> bf16, vectorized (total must be multiple of 4)
__global__ void cvt4_kernel(const float* __restrict__ in, unsigned short* __restrict__ out, int total4){
  int idx = blockIdx.x*256 + threadIdx.x;
  if (idx >= total4) return;
  float4 v = ((const float4*)in)[idx];
  ushort4 u;
  u.x = f2bf(v.x); u.y = f2bf(v.y); u.z = f2bf(v.z); u.w = f2bf(v.w);
  ((ushort4*)out)[idx] = u;
}

// WT[c][k] bf16, c in [0,2M): cols of Wl then Wr, k zero-padded to Kpad
__global__ void prepW_kernel(const float* __restrict__ Wl, const float* __restrict__ Wr,
                             unsigned short* __restrict__ WT, int M, int K, int Kpad){
  int idx = blockIdx.x*256 + threadIdx.x;
  if (idx >= 2*M*Kpad) return;
  int c = idx / Kpad, k = idx - c*Kpad;
  float v = 0.f;
  if (k < K) v = (c < M) ? Wl[(size_t)k*M + c] : Wr[(size_t)k*M + (c - M)];
  WT[idx] = f2bf(v);
}

// ---------------- dual MFMA bf16 GEMM ----------------
// O[:, 0:Mhalf] = X @ Wl -> bf16 outBF (row stride Mhalf)
// O[:, Mhalf:2*Mhalf] = X @ Wr -> fp32 outF (row stride Mhalf)
// Xbf [N, Kpad] bf16; WT [2*Mhalf, Kpad] bf16 (pre-transposed).
// 128x128 tile, 4 waves 2x2, each wave 64x64 = 4x4 mfma 16x16x32.
// LDS rows of 40 halves (80 B): b128 store/load start banks (20r+4g)%32 -> conflict-free.

__global__ __launch_bounds__(256) void gemm_dual(const unsigned short* __restrict__ Xbf,
                                                 const unsigned short* __restrict__ WT,
                                                 unsigned short* __restrict__ outBF,
                                                 float* __restrict__ outF,
                                                 int N, int Kpad, int Mhalf){
  __shared__ __attribute__((aligned(16))) unsigned short Xs[128*40];
  __shared__ __attribute__((aligned(16))) unsigned short Ws[128*40];
  int t = threadIdx.x;
  int n0 = blockIdx.x*128, c0 = blockIdx.y*128;
  int wv = t >> 6, lane = t & 63;
  int wr = wv >> 1, wc = wv & 1;
  int m16 = lane & 15, quad = lane >> 4;

  ffrag acc[4][4];
  #pragma unroll
  for (int i = 0; i < 4; i++)
    #pragma unroll
    for (int j = 0; j < 4; j++) acc[i][j] = (ffrag){0.f,0.f,0.f,0.f};

  for (int k0 = 0; k0 < Kpad; k0 += 32){
    uint4 zero = {0,0,0,0};
    #pragma unroll
    for (int it = 0; it < 2; it++){
      int idx = t + it*256;
      int r = idx >> 2, g = idx & 3;
      int n = n0 + r;
      uint4 v = (n < N) ? *(const uint4*)&Xbf[(size_t)n*Kpad + k0 + g*8] : zero;
      *(uint4*)&Xs[r*40 + g*8] = v;
    }
    #pragma unroll
    for (int it = 0; it < 2; it++){
      int idx = t + it*256;
      int c = idx >> 2, g = idx & 3;
      uint4 v = *(const uint4*)&WT[(size_t)(c0 + c)*Kpad + k0 + g*8];
      *(uint4*)&Ws[c*40 + g*8] = v;
    }
    __syncthreads();
    bfrag a[4], b[4];
    #pragma unroll
    for (int i = 0; i < 4; i++)
      a[i] = *(const bfrag*)&Xs[(wr*64 + i*16 + m16)*40 + quad*8];
    #pragma unroll
    for (int j = 0; j < 4; j++)
      b[j] = *(const bfrag*)&Ws[(wc*64 + j*16 + m16)*40 + quad*8];
    #pragma unroll
    for (int i = 0; i < 4; i++)
      #pragma unroll
      for (int j = 0; j < 4; j++)
        acc[i][j] = __builtin_amdgcn_mfma_f32_16x16x32_bf16(a[i], b[j], acc[i][j], 0, 0, 0);
    __syncthreads();
  }

  bool isBF = (c0 < Mhalf);
  int ccol0 = isBF ? c0 : (c0 - Mhalf);
  #pragma unroll
  for (int i = 0; i < 4; i++){
    #pragma unroll
    for (int reg = 0; reg < 4; reg++){
      int rr = n0 + wr*64 + i*16 + quad*4 + reg;
      if (rr >= N) continue;
      #pragma unroll
      for (int j = 0; j < 4; j++){
        int cc = ccol0 + wc*64 + j*16 + m16;
        float v = acc[i][j][reg];
        if (isBF) outBF[(size_t)rr*Mhalf + cc] = f2bf(v);
        else      outF [(size_t)rr*Mhalf + cc] = v;
      }
    }
  }
}

// ---------------- fused GATv2 edge phase: wave-per-node, depth-4 pipeline ----------------

#define EDGE2(XU) { \
  float x0=bf2f(XU.x), x1=bf2f(XU.y), x2=bf2f(XU.z), x3=bf2f(XU.w); \
  float e0=x0+xrv.x; e0=LEAKY(e0); \
  float e1=x1+xrv.y; e1=LEAKY(e1); \
  float e2=x2+xrv.z; e2=LEAKY(e2); \
  float e3=x3+xrv.w; e3=LEAKY(e3); \
  float dot=e0*attv.x+e1*attv.y+e2*attv.z+e3*attv.w; \
  dot += __shfl_xor(dot,16); dot += __shfl_xor(dot,8); dot += __shfl_xor(dot,4); \
  dot += __shfl_xor(dot,2);  dot += __shfl_xor(dot,1); \
  float nm=fmaxf(m,dot); float sc=__expf(m-nm); float w_=__expf(dot-nm); \
  l=l*sc+w_; \
  acc.x=acc.x*sc+w_*x0; acc.y=acc.y*sc+w_*x1; acc.z=acc.z*sc+w_*x2; acc.w=acc.w*sc+w_*x3; \
  m=nm; }

__global__ __launch_bounds__(256) void fused_gat_wave2(
    const int* __restrict__ row_off, const int* __restrict__ csr_src,
    const unsigned short* __restrict__ xlbf, const float* __restrict__ xr,
    const float* __restrict__ att, const float* __restrict__ bias,
    float* __restrict__ out, int N)
{
  int n = blockIdx.x*4 + (threadIdx.x >> 6);
  if (n >= N) return;
  int lane = threadIdx.x & 63;
  int r0 = row_off[n], r1 = row_off[n+1];
  const ushort4* xl4 = (const ushort4*)xlbf;
  float4 xrv = ((const float4*)xr)[(size_t)n*64 + lane];
  float4 attv = ((const float4*)att)[lane];
  float m = -INFINITY, l = 0.f;
  float4 acc = {0.f,0.f,0.f,0.f};

  if (r1 > r0){
    ushort4 z; z.x = z.y = z.z = z.w = 0;
    ushort4 c0v=z, c1v=z, c2v=z, c3v=z, n0v=z, n1v=z, n2v=z, n3v=z;
    if (r0+0 < r1) c0v = xl4[(size_t)csr_src[r0+0]*64 + lane];
    if (r0+1 < r1) c1v = xl4[(size_t)csr_src[r0+1]*64 + lane];
    if (r0+2 < r1) c2v = xl4[(size_t)csr_src[r0+2]*64 + lane];
    if (r0+3 < r1) c3v = xl4[(size_t)csr_src[r0+3]*64 + lane];
    for (int base = r0; base < r1; base += 4){
      int nb = base + 4;
      if (nb+0 < r1) n0v = xl4[(size_t)csr_src[nb+0]*64 + lane];
      if (nb+1 < r1) n1v = xl4[(size_t)csr_src[nb+1]*64 + lane];
      if (nb+2 < r1) n2v = xl4[(size_t)csr_src[nb+2]*64 + lane];
      if (nb+3 < r1) n3v = xl4[(size_t)csr_src[nb+3]*64 + lane];
      int cnt = r1 - base;
      EDGE2(c0v);
      if (cnt > 1) EDGE2(c1v);
      if (cnt > 2) EDGE2(c2v);
      if (cnt > 3) EDGE2(c3v);
      c0v = n0v; c1v = n1v; c2v = n2v; c3v = n3v;
    }
  }
  float4 bv = ((const float4*)bias)[lane];
  float4 res = bv;
  if (r1 > r0){
    float inv = 1.f / (l * (float)(r1 - r0));
    res.x += acc.x*inv; res.y += acc.y*inv; res.z += acc.z*inv; res.w += acc.w*inv;
  }
  ((float4*)out)[(size_t)n*64 + lane] = res;
}

#define EDGE1(XU) { \
  float x0=bf2f(XU.x), x1=bf2f(XU.y); \
  float e0=x0+xrv.x; e0=LEAKY(e0); \
  float e1=x1+xrv.y; e1=LEAKY(e1); \
  float dot=e0*attv.x+e1*attv.y; \
  dot += __shfl_xor(dot,32); dot += __shfl_xor(dot,16); dot += __shfl_xor(dot,8); \
  dot += __shfl_xor(dot,4);  dot += __shfl_xor(dot,2);  dot += __shfl_xor(dot,1); \
  float nm=fmaxf(m,dot); float sc=__expf(m-nm); float w_=__expf(dot-nm); \
  l=l*sc+w_; \
  acc.x=acc.x*sc+w_*x0; acc.y=acc.y*sc+w_*x1; \
  m=nm; }

__global__ __launch_bounds__(256) void fused_gat_wave1(
    const int* __restrict__ row_off, const int* __restrict__ csr_src,
    const unsigned short* __restrict__ xlbf, const float* __restrict__ xr,
    const float* __restrict__ att, const float* __restrict__ bias,
    float* __restrict__ out, int N)
{
  int n = blockIdx.x*4 + (threadIdx.x >> 6);
  if (n >= N) return;
  int lane = threadIdx.x & 63;
  int r0 = row_off[n], r1 = row_off[n+1];
  const ushort2* xl2 = (const ushort2*)xlbf;
  float2 xrv = ((const float2*)xr)[(size_t)n*64 + lane];
  float2 attv = ((const float2*)att)[lane];
  float m = -INFINITY, l = 0.f;
  float2 acc = {0.f,0.f};

  if (r1 > r0){
    ushort2 z; z.x = z.y = 0;
    ushort2 c0v=z, c1v=z, c2v=z, c3v=z, n0v=z, n1v=z, n2v=z, n3v=z;
    if (r0+0 < r1) c0v = xl2[(size_t)csr_src[r0+0]*64 + lane];
    if (r0+1 < r1) c1v = xl2[(size_t)csr_src[r0+1]*64 + lane];
    if (r0+2 < r1) c2v = xl2[(size_t)csr_src[r0+2]*64 + lane];
    if (r0+3 < r1) c3v = xl2[(size_t)csr_src[r0+3]*64 + lane];
    for (int base = r0; base < r1; base += 4){
      int nb = base + 4;
      if (nb+0 < r1) n0v = xl2[(size_t)csr_src[nb+0]*64 + lane];
      if (nb+1 < r1) n1v = xl2[(size_t)csr_src[nb+1]*64 + lane];
      if (nb+2 < r1) n2v = xl2[(size_t)csr_src[nb+2]*64 + lane];
      if (nb+3 < r1) n3v = xl2[(size_t)csr_src[nb+3]*64 + lane];
      int cnt = r1 - base;
      EDGE1(c0v);
      if (cnt > 1) EDGE1(c1v);
      if (cnt > 2) EDGE1(c2v);
      if (cnt > 3) EDGE1(c3v);
      c0v = n0v; c1v = n1v; c2v = n2v; c3v = n3v;
    }
  }
  float2 bv = ((const float2*)bias)[lane];
  float2 res = bv;
  if (r1 > r0){
    float inv = 1.f / (l * (float)(r1 - r0));
    res.x += acc.x*inv; res.y += acc.y*inv;
  }
  ((float2*)out)[(size_t)n*64 + lane] = res;
}

// ---------------- layer 3 (C=1) ----------------

__global__ __launch_bounds__(256) void gemm3_kernel(const float* __restrict__ h2,
                                                    const float* __restrict__ W3l,
                                                    const float* __restrict__ W3r,
                                                    float* __restrict__ xl3,
                                                    float* __restrict__ xr3, int N){
  int n = blockIdx.x*4 + (threadIdx.x >> 6);
  int lane = threadIdx.x & 63;
  if (n >= N) return;
  float v1 = h2[(size_t)n*128 + lane];
  float v2 = h2[(size_t)n*128 + 64 + lane];
  float al = v1*W3l[lane] + v2*W3l[64 + lane];
  float ar = v1*W3r[lane] + v2*W3r[64 + lane];
  #pragma unroll
  for (int off = 32; off > 0; off >>= 1){
    al += __shfl_down(al, off);
    ar += __shfl_down(ar, off);
  }
  if (lane == 0){ xl3[n] = al; xr3[n] = ar; }
}

// wave-per-node, lane-per-edge online softmax for C=1
__global__ __launch_bounds__(256) void aggr3_wave(
    const int* __restrict__ row_off, const int* __restrict__ csr_src,
    const float* __restrict__ xl3, const float* __restrict__ xr3,
    const float* __restrict__ a3, const float* __restrict__ b3,
    float* __restrict__ h3, int N)
{
  int n = blockIdx.x*4 + (threadIdx.x >> 6);
  if (n >= N) return;
  int lane = threadIdx.x & 63;
  int r0 = row_off[n], r1 = row_off[n+1];
  int deg = r1 - r0;
  float b = b3[0];
  if (deg == 0){ if (lane == 0) h3[n] = b; return; }
  float xr = xr3[n];
  float aa = a3[0];
  float m = -INFINITY, den = 0.f, s = 0.f;
  for (int base = r0; base < r1; base += 64){
    int p = base + lane;
    bool valid = p < r1;
    float xlv = valid ? xl3[csr_src[p]] : 0.f;
    float v = xlv + xr;
    v = LEAKY(v) * aa;
    if (!valid) v = -INFINITY;
    float bm = v;
    #pragma unroll
    for (int off = 32; off > 0; off >>= 1) bm = fmaxf(bm, __shfl_xor(bm, off));
    float nm = fmaxf(m, bm);
    float a = valid ? __expf(v - nm) : 0.f;
    float bd = a, bs = a * xlv;
    #pragma unroll
    for (int off = 32; off > 0; off >>= 1){
      bd += __shfl_xor(bd, off);
      bs += __shfl_xor(bs, off);
    }
    float sc = __expf(m - nm);   // 0 on first batch
    den = den*sc + bd;
    s   = s*sc + bs;
    m = nm;
  }
  if (lane == 0) h3[n] = s/den/(float)deg + b;
}

__global__ void out_kernel(const float* __restrict__ h3, const float* __restrict__ y,
                           const int* __restrict__ tidx, float* __restrict__ out, int T){
  int i = blockIdx.x*256 + threadIdx.x;
  if (i >= T) return;
  int n = tidx[i];
  out[i] = 1.f/(1.f + __expf(-h3[n]));
  out[T + i] = y[n];
}

// ---------------- launch ----------------

extern "C" void kernel_launch(void* const* d_in, const int* in_sizes, int n_in,
                              void* d_out, int out_size, void* d_ws, size_t ws_size,
                              hipStream_t stream){
  const float* x    = (const float*)d_in[0];
  const int*   ei   = (const int*)d_in[1];
  const float* y    = (const float*)d_in[2];
  const int*   tidx = (const int*)d_in[3];
  const float* W1l  = (const float*)d_in[4];
  const float* W1r  = (const float*)d_in[5];
  const float* a1   = (const float*)d_in[6];
  const float* b1   = (const float*)d_in[7];
  const float* W2l  = (const float*)d_in[8];
  const float* W2r  = (const float*)d_in[9];
  const float* a2   = (const float*)d_in[10];
  const float* b2   = (const float*)d_in[11];
  const float* W3l  = (const float*)d_in[12];
  const float* W3r  = (const float*)d_in[13];
  const float* a3   = (const float*)d_in[14];
  const float* b3   = (const float*)d_in[15];

  int N = in_sizes[2];        // 50000 nodes
  int E = in_sizes[1] / 2;    // 800000 edges
  int T = in_sizes[3];        // 40000 train indices
  const int* src = ei;
  const int* dst = ei + E;

  char* w = (char*)d_ws;
  size_t off = 0;
  auto take = [&](size_t bytes) -> char* {
    char* p = w + off;
    off = (off + bytes + 255) & ~(size_t)255;
    return p;
  };
  int*   row_off = (int*)  take((size_t)(N+1)*4);
  int*   degi    = (int*)  take((size_t)N*4);
  int*   cursor  = (int*)  take((size_t)N*4);
  int*   csr_src = (int*)  take((size_t)E*4);
  unsigned short* WT1 = (unsigned short*)take((size_t)512*160*2);
  unsigned short* WT2 = (unsigned short*)take((size_t)256*256*2);
  float* A       = (float*)take((size_t)N*256*4);
  float* B       = (float*)take((size_t)N*256*4);

  // ---- CSR build (graph shared by all 3 layers) ----
  hipMemsetAsync(degi, 0, (size_t)N*4, stream);
  hipMemsetAsync(cursor, 0, (size_t)N*4, stream);
  deg_kernel<<<(E+255)/256, 256, 0, stream>>>(dst, degi, E);
  scan_kernel<<<1, 1024, 0, stream>>>(degi, row_off, N);
  scatter_kernel<<<(E+255)/256, 256, 0, stream>>>(src, dst, row_off, cursor, csr_src, E);

  // ---- layer 1: 129 -> 256 (H=2, C=128), Kpad=160 ----
  unsigned short* xl1bf = (unsigned short*)A;                   // A lower: N*256 bf16
  unsigned short* Xbf   = (unsigned short*)(A + (size_t)N*128); // A upper: N*160 bf16
  float*          xr1   = B;                                    // N*256 f32
  cvt_pad_kernel<<<(N*160+255)/256, 256, 0, stream>>>(x, Xbf, N, 129, 160);
  prepW_kernel<<<(2*256*160+255)/256, 256, 0, stream>>>(W1l, W1r, WT1, 256, 129, 160);
  gemm_dual<<<dim3((N+127)/128, 4), 256, 0, stream>>>(Xbf, WT1, xl1bf, xr1, N, 160, 256);
  fused_gat_wave2<<<(N+3)/4, 256, 0, stream>>>(row_off, csr_src, xl1bf, xr1, a1, b1, B, N);
  float* h1 = B;

  // ---- layer 2: 256 -> 128 (H=1, C=128), Kpad=256 ----
  unsigned short* h1bf  = (unsigned short*)A;                   // A lower (xl1bf dead)
  unsigned short* xl2bf = (unsigned short*)(A + (size_t)N*128); // A upper (Xbf dead): N*128 bf16
  float*          xr2   = B;                                    // B lower (h1 dead after cvt)
  cvt4_kernel<<<(N*64+255)/256, 256, 0, stream>>>(h1, h1bf, N*64);
  prepW_kernel<<<(2*128*256+255)/256, 256, 0, stream>>>(W2l, W2r, WT2, 128, 256, 256);
  gemm_dual<<<dim3((N+127)/128, 2), 256, 0, stream>>>(h1bf, WT2, xl2bf, xr2, N, 256, 128);
  fused_gat_wave1<<<(N+3)/4, 256, 0, stream>>>(row_off, csr_src, xl2bf, xr2, a2, b2, xr2, N);
  float* h2 = xr2;

  // ---- layer 3: 128 -> 1 (H=1, C=1) ----
  float* Bu  = B + (size_t)N*128;   // B upper (free)
  float* xl3 = Bu;
  float* xr3 = Bu + N;
  float* h3  = Bu + 2*(size_t)N;
  gemm3_kernel<<<(N+3)/4, 256, 0, stream>>>(h2, W3l, W3r, xl3, xr3, N);
  aggr3_wave<<<(N+3)/4, 256, 0, stream>>>(row_off, csr_src, xl3, xr3, a3, b3, h3, N);

  // ---- output: (sigmoid(h3)[tidx], y[tidx]) ----
  out_kernel<<<(T+255)/256, 256, 0, stream>>>(h3, y, tidx, (float*)d_out, T);
}

// Round 7
// 508.930 us; speedup vs baseline: 2.0285x; 1.1030x over previous
//
#include <hip/hip_runtime.h>
#include <cmath>

__device__ __forceinline__ float lo16(unsigned u){ union{unsigned x; float f;} c; c.x = u << 16; return c.f; }
__device__ __forceinline__ float hi16(unsigned u){ union{unsigned x; float f;} c; c.x = u & 0xffff0000u; return c.f; }
__device__ __forceinline__ float leaky(float v){ return fmaxf(v, 0.2f*v); }
__device__ __forceinline__ unsigned short f2bf(float f){
  union { float f; unsigned u; } c; c.f = f;
  unsigned u = c.u + 0x7FFFu + ((c.u >> 16) & 1u);
  return (unsigned short)(u >> 16);
}
// safe merge factor: returns exp(m-M), giving 1 when m==M (handles -inf==-inf)
__device__ __forceinline__ float mergef(float m, float M){ return (m == M) ? 1.f : __expf(m - M); }

typedef __attribute__((ext_vector_type(8))) short bfrag;   // 8 bf16 = 4 VGPR
typedef __attribute__((ext_vector_type(4))) float ffrag;   // 4 f32 acc

// ---------------- CSR build ----------------

__global__ void deg_kernel(const int* __restrict__ dst, int* __restrict__ degi, int E){
  int e = blockIdx.x*256 + threadIdx.x;
  if (e < E) atomicAdd(&degi[dst[e]], 1);
}

__global__ void scan_kernel(const int* __restrict__ degi, int* __restrict__ row_off, int N){
  __shared__ int part[1024];
  int t = threadIdx.x;
  int chunk = (N + 1023) >> 10;
  int s0 = t*chunk, s1 = min(s0 + chunk, N);
  int sum = 0;
  for (int i = s0; i < s1; i++) sum += degi[i];
  part[t] = sum; __syncthreads();
  for (int off = 1; off < 1024; off <<= 1){
    int v = (t >= off) ? part[t - off] : 0;
    __syncthreads();
    part[t] += v;
    __syncthreads();
  }
  int run = (t == 0) ? 0 : part[t-1];
  for (int i = s0; i < s1; i++){ row_off[i] = run; run += degi[i]; }
  if (t == 1023) row_off[N] = run;
}

__global__ void scatter_kernel(const int* __restrict__ src, const int* __restrict__ dst,
                               const int* __restrict__ row_off, int* __restrict__ cursor,
                               int* __restrict__ csr_src, int E){
  int e = blockIdx.x*256 + threadIdx.x;
  if (e < E){
    int d = dst[e];
    int pos = row_off[d] + atomicAdd(&cursor[d], 1);
    csr_src[pos] = src[e];
  }
}

// ---------------- precision-prep kernels ----------------

__global__ void cvt_pad_kernel(const float* __restrict__ in, unsigned short* __restrict__ out,
                               int N, int K, int Kpad){
  int idx = blockIdx.x*256 + threadIdx.x;
  if (idx >= N*Kpad) return;
  int n = idx / Kpad, k = idx - n*Kpad;
  out[idx] = (k < K) ? f2bf(in[(size_t)n*K + k]) : (unsigned short)0;
}

__global__ void cvt4_kernel(const float* __restrict__ in, unsigned short* __restrict__ out, int total4){
  int idx = blockIdx.x*256 + threadIdx.x;
  if (idx >= total4) return;
  float4 v = ((const float4*)in)[idx];
  ushort4 u;
  u.x = f2bf(v.x); u.y = f2bf(v.y); u.z = f2bf(v.z); u.w = f2bf(v.w);
  ((ushort4*)out)[idx] = u;
}

__global__ void prepW_kernel(const float* __restrict__ Wl, const float* __restrict__ Wr,
                             unsigned short* __restrict__ WT, int M, int K, int Kpad){
  int idx = blockIdx.x*256 + threadIdx.x;
  if (idx >= 2*M*Kpad) return;
  int c = idx / Kpad, k = idx - c*Kpad;
  float v = 0.f;
  if (k < K) v = (c < M) ? Wl[(size_t)k*M + c] : Wr[(size_t)k*M + (c - M)];
  WT[idx] = f2bf(v);
}

// ---------------- dual MFMA bf16 GEMM, CB col-tiles of 128 per block ----------------
// cols [0,Mhalf) -> bf16 outBF; cols [Mhalf,2*Mhalf) -> fp32 outF (row stride Mhalf each).

template<int CB>
__global__ __launch_bounds__(256) void gemm_dual(const unsigned short* __restrict__ Xbf,
                                                 const unsigned short* __restrict__ WT,
                                                 unsigned short* __restrict__ outBF,
                                                 float* __restrict__ outF,
                                                 int N, int Kpad, int Mhalf){
  __shared__ __attribute__((aligned(16))) unsigned short Xs[128*40];
  __shared__ __attribute__((aligned(16))) unsigned short Ws[CB*128*40];
  int t = threadIdx.x;
  int n0 = blockIdx.x*128, c0 = blockIdx.y*(CB*128);
  int wv = t >> 6, lane = t & 63;
  int wr = wv >> 1, wc = wv & 1;
  int m16 = lane & 15, quad = lane >> 4;

  ffrag acc[CB][4][4];
  #pragma unroll
  for (int cb = 0; cb < CB; cb++)
    #pragma unroll
    for (int i = 0; i < 4; i++)
      #pragma unroll
      for (int j = 0; j < 4; j++) acc[cb][i][j] = (ffrag){0.f,0.f,0.f,0.f};

  for (int k0 = 0; k0 < Kpad; k0 += 32){
    uint4 zero = {0,0,0,0};
    #pragma unroll
    for (int it = 0; it < 2; it++){
      int idx = t + it*256;
      int r = idx >> 2, g = idx & 3;
      int n = n0 + r;
      uint4 v = (n < N) ? *(const uint4*)&Xbf[(size_t)n*Kpad + k0 + g*8] : zero;
      *(uint4*)&Xs[r*40 + g*8] = v;
    }
    #pragma unroll
    for (int it = 0; it < 2*CB; it++){
      int idx = t + it*256;
      int c = idx >> 2, g = idx & 3;
      uint4 v = *(const uint4*)&WT[(size_t)(c0 + c)*Kpad + k0 + g*8];
      *(uint4*)&Ws[c*40 + g*8] = v;
    }
    __syncthreads();
    bfrag a[4];
    #pragma unroll
    for (int i = 0; i < 4; i++)
      a[i] = *(const bfrag*)&Xs[(wr*64 + i*16 + m16)*40 + quad*8];
    #pragma unroll
    for (int cb = 0; cb < CB; cb++){
      bfrag b[4];
      #pragma unroll
      for (int j = 0; j < 4; j++)
        b[j] = *(const bfrag*)&Ws[(cb*128 + wc*64 + j*16 + m16)*40 + quad*8];
      #pragma unroll
      for (int i = 0; i < 4; i++)
        #pragma unroll
        for (int j = 0; j < 4; j++)
          acc[cb][i][j] = __builtin_amdgcn_mfma_f32_16x16x32_bf16(a[i], b[j], acc[cb][i][j], 0, 0, 0);
    }
    __syncthreads();
  }

  #pragma unroll
  for (int cb = 0; cb < CB; cb++){
    int gc0 = c0 + cb*128;
    bool isBF = (gc0 < Mhalf);
    int ccol0 = isBF ? gc0 : (gc0 - Mhalf);
    #pragma unroll
    for (int i = 0; i < 4; i++){
      #pragma unroll
      for (int reg = 0; reg < 4; reg++){
        int rr = n0 + wr*64 + i*16 + quad*4 + reg;
        if (rr >= N) continue;
        #pragma unroll
        for (int j = 0; j < 4; j++){
          int cc = ccol0 + wc*64 + j*16 + m16;
          float v = acc[cb][i][j][reg];
          if (isBF) outBF[(size_t)rr*Mhalf + cc] = f2bf(v);
          else      outF [(size_t)rr*Mhalf + cc] = v;
        }
      }
    }
  }
}

// ---------------- fused GATv2 edge phase ----------------
// H=2, CH=256: wave per node, 2 edge slots x 32 lanes (16/head), 8 ch/lane.
// out may alias xr: wave n reads only xr row n (at start), writes only out row n.

__global__ __launch_bounds__(256) void fused_gat_wave2(
    const int* __restrict__ row_off, const int* __restrict__ csr_src,
    const unsigned short* __restrict__ xlbf, const float* __restrict__ xr,
    const float* __restrict__ att, const float* __restrict__ bias,
    float* __restrict__ out, int N)
{
  int n = blockIdx.x*4 + (threadIdx.x >> 6);
  if (n >= N) return;
  int lane = threadIdx.x & 63;
  int slot = lane >> 5;         // 2 edge slots
  int sub  = lane & 31;         // covers 256 ch: ch0 = sub*8
  int ch0  = sub*8;
  int r0 = row_off[n], r1 = row_off[n+1];
  int deg = r1 - r0;

  const float4* xrp = (const float4*)(xr + (size_t)n*256 + ch0);
  float4 xra = xrp[0], xrb = xrp[1];
  const float4* atp = (const float4*)(att + ch0);
  float4 ata = atp[0], atb = atp[1];

  float m = -INFINITY, l = 0.f;
  float a0=0.f,a1=0.f,a2=0.f,a3=0.f,a4=0.f,a5=0.f,a6=0.f,a7=0.f;

  if (deg > 0){
    int p = r0 + slot;
    int pc = min(p, r1-1);
    uint4 cur = *(const uint4*)&xlbf[(size_t)csr_src[pc]*256 + ch0];
    for (; p < r1; p += 2){
      int pn = min(p+2, r1-1);
      uint4 nxt = *(const uint4*)&xlbf[(size_t)csr_src[pn]*256 + ch0];
      float x0=lo16(cur.x), x1=hi16(cur.x), x2=lo16(cur.y), x3=hi16(cur.y);
      float x4=lo16(cur.z), x5=hi16(cur.z), x6=lo16(cur.w), x7=hi16(cur.w);
      float dot = leaky(x0+xra.x)*ata.x + leaky(x1+xra.y)*ata.y
                + leaky(x2+xra.z)*ata.z + leaky(x3+xra.w)*ata.w
                + leaky(x4+xrb.x)*atb.x + leaky(x5+xrb.y)*atb.y
                + leaky(x6+xrb.z)*atb.z + leaky(x7+xrb.w)*atb.w;
      dot += __shfl_xor(dot, 8);
      dot += __shfl_xor(dot, 4);
      dot += __shfl_xor(dot, 2);
      dot += __shfl_xor(dot, 1);   // per-16-lane (head) logit
      float nm = fmaxf(m, dot);
      float sc = __expf(m - nm);   // 0 on first edge
      float w_ = __expf(dot - nm);
      l = l*sc + w_;
      a0 = a0*sc + w_*x0; a1 = a1*sc + w_*x1; a2 = a2*sc + w_*x2; a3 = a3*sc + w_*x3;
      a4 = a4*sc + w_*x4; a5 = a5*sc + w_*x5; a6 = a6*sc + w_*x6; a7 = a7*sc + w_*x7;
      m = nm;
      cur = nxt;
    }
  }

  const float4* bvp = (const float4*)(bias + ch0);
  float4 res0 = bvp[0], res1 = bvp[1];
  if (deg > 0){
    // merge the two slots (flash-combine)
    float m2 = __shfl_xor(m, 32);
    float l2 = __shfl_xor(l, 32);
    float M  = fmaxf(m, m2);
    float fa = mergef(m, M), fb = mergef(m2, M);
    float L  = l*fa + l2*fb;
    float q;
    q = __shfl_xor(a0,32); a0 = a0*fa + q*fb;
    q = __shfl_xor(a1,32); a1 = a1*fa + q*fb;
    q = __shfl_xor(a2,32); a2 = a2*fa + q*fb;
    q = __shfl_xor(a3,32); a3 = a3*fa + q*fb;
    q = __shfl_xor(a4,32); a4 = a4*fa + q*fb;
    q = __shfl_xor(a5,32); a5 = a5*fa + q*fb;
    q = __shfl_xor(a6,32); a6 = a6*fa + q*fb;
    q = __shfl_xor(a7,32); a7 = a7*fa + q*fb;
    float inv = 1.f / (L * (float)deg);
    res0.x += a0*inv; res0.y += a1*inv; res0.z += a2*inv; res0.w += a3*inv;
    res1.x += a4*inv; res1.y += a5*inv; res1.z += a6*inv; res1.w += a7*inv;
  }
  if (slot == 0){
    float4* op = (float4*)(out + (size_t)n*256 + ch0);
    op[0] = res0; op[1] = res1;
  }
}

// H=1, CH=128: wave per node, 4 edge slots x 16 lanes, 8 ch/lane.

__global__ __launch_bounds__(256) void fused_gat_wave1(
    const int* __restrict__ row_off, const int* __restrict__ csr_src,
    const unsigned short* __restrict__ xlbf, const float* __restrict__ xr,
    const float* __restrict__ att, const float* __restrict__ bias,
    float* __restrict__ out, int N)
{
  int n = blockIdx.x*4 + (threadIdx.x >> 6);
  if (n >= N) return;
  int lane = threadIdx.x & 63;
  int slot = lane >> 4;         // 4 edge slots
  int sub  = lane & 15;         // ch0 = sub*8, covers 128
  int ch0  = sub*8;
  int r0 = row_off[n], r1 = row_off[n+1];
  int deg = r1 - r0;

  const float4* xrp = (const float4*)(xr + (size_t)n*128 + ch0);
  float4 xra = xrp[0], xrb = xrp[1];
  const float4* atp = (const float4*)(att + ch0);
  float4 ata = atp[0], atb = atp[1];

  float m = -INFINITY, l = 0.f;
  float a0=0.f,a1=0.f,a2=0.f,a3=0.f,a4=0.f,a5=0.f,a6=0.f,a7=0.f;

  if (deg > 0){
    int p = r0 + slot;
    int pc = min(p, r1-1);
    uint4 cur = *(const uint4*)&xlbf[(size_t)csr_src[pc]*128 + ch0];
    for (; p < r1; p += 4){
      int pn = min(p+4, r1-1);
      uint4 nxt = *(const uint4*)&xlbf[(size_t)csr_src[pn]*128 + ch0];
      float x0=lo16(cur.x), x1=hi16(cur.x), x2=lo16(cur.y), x3=hi16(cur.y);
      float x4=lo16(cur.z), x5=hi16(cur.z), x6=lo16(cur.w), x7=hi16(cur.w);
      float dot = leaky(x0+xra.x)*ata.x + leaky(x1+xra.y)*ata.y
                + leaky(x2+xra.z)*ata.z + leaky(x3+xra.w)*ata.w
                + leaky(x4+xrb.x)*atb.x + leaky(x5+xrb.y)*atb.y
                + leaky(x6+xrb.z)*atb.z + leaky(x7+xrb.w)*atb.w;
      dot += __shfl_xor(dot, 8);
      dot += __shfl_xor(dot, 4);
      dot += __shfl_xor(dot, 2);
      dot += __shfl_xor(dot, 1);   // per-16-lane logit
      float nm = fmaxf(m, dot);
      float sc = __expf(m - nm);
      float w_ = __expf(dot - nm);
      l = l*sc + w_;
      a0 = a0*sc + w_*x0; a1 = a1*sc + w_*x1; a2 = a2*sc + w_*x2; a3 = a3*sc + w_*x3;
      a4 = a4*sc + w_*x4; a5 = a5*sc + w_*x5; a6 = a6*sc + w_*x6; a7 = a7*sc + w_*x7;
      m = nm;
      cur = nxt;
    }
  }

  const float4* bvp = (const float4*)(bias + ch0);
  float4 res0 = bvp[0], res1 = bvp[1];
  if (deg > 0){
    // two-stage merge: xor16 (slot pairs), then xor32
    #pragma unroll
    for (int stage = 0; stage < 2; stage++){
      int d = 16 << stage;
      float m2 = __shfl_xor(m, d);
      float l2 = __shfl_xor(l, d);
      float M  = fmaxf(m, m2);
      float fa = mergef(m, M), fb = mergef(m2, M);
      l = l*fa + l2*fb;
      float q;
      q = __shfl_xor(a0,d); a0 = a0*fa + q*fb;
      q = __shfl_xor(a1,d); a1 = a1*fa + q*fb;
      q = __shfl_xor(a2,d); a2 = a2*fa + q*fb;
      q = __shfl_xor(a3,d); a3 = a3*fa + q*fb;
      q = __shfl_xor(a4,d); a4 = a4*fa + q*fb;
      q = __shfl_xor(a5,d); a5 = a5*fa + q*fb;
      q = __shfl_xor(a6,d); a6 = a6*fa + q*fb;
      q = __shfl_xor(a7,d); a7 = a7*fa + q*fb;
      m = M;
    }
    float inv = 1.f / (l * (float)deg);
    res0.x += a0*inv; res0.y += a1*inv; res0.z += a2*inv; res0.w += a3*inv;
    res1.x += a4*inv; res1.y += a5*inv; res1.z += a6*inv; res1.w += a7*inv;
  }
  if (slot == 0){
    float4* op = (float4*)(out + (size_t)n*128 + ch0);
    op[0] = res0; op[1] = res1;
  }
}

// ---------------- layer 3 (C=1) ----------------

__global__ __launch_bounds__(256) void gemm3_kernel(const float* __restrict__ h2,
                                                    const float* __restrict__ W3l,
                                                    const float* __restrict__ W3r,
                                                    float* __restrict__ xl3,
                                                    float* __restrict__ xr3, int N){
  int n = blockIdx.x*4 + (threadIdx.x >> 6);
  int lane = threadIdx.x & 63;
  if (n >= N) return;
  float v1 = h2[(size_t)n*128 + lane];
  float v2 = h2[(size_t)n*128 + 64 + lane];
  float al = v1*W3l[lane] + v2*W3l[64 + lane];
  float ar = v1*W3r[lane] + v2*W3r[64 + lane];
  #pragma unroll
  for (int off = 32; off > 0; off >>= 1){
    al += __shfl_down(al, off);
    ar += __shfl_down(ar, off);
  }
  if (lane == 0){ xl3[n] = al; xr3[n] = ar; }
}

__global__ __launch_bounds__(256) void aggr3_wave(
    const int* __restrict__ row_off, const int* __restrict__ csr_src,
    const float* __restrict__ xl3, const float* __restrict__ xr3,
    const float* __restrict__ a3, const float* __restrict__ b3,
    float* __restrict__ h3, int N)
{
  int n = blockIdx.x*4 + (threadIdx.x >> 6);
  if (n >= N) return;
  int lane = threadIdx.x & 63;
  int r0 = row_off[n], r1 = row_off[n+1];
  int deg = r1 - r0;
  float b = b3[0];
  if (deg == 0){ if (lane == 0) h3[n] = b; return; }
  float xrv = xr3[n];
  float aa = a3[0];
  float m = -INFINITY, den = 0.f, s = 0.f;
  for (int base = r0; base < r1; base += 64){
    int p = base + lane;
    bool valid = p < r1;
    float xlv = valid ? xl3[csr_src[p]] : 0.f;
    float v = leaky(xlv + xrv) * aa;
    if (!valid) v = -INFINITY;
    float bm = v;
    #pragma unroll
    for (int off = 32; off > 0; off >>= 1) bm = fmaxf(bm, __shfl_xor(bm, off));
    float nm = fmaxf(m, bm);
    float a = valid ? __expf(v - nm) : 0.f;
    float bd = a, bs = a * xlv;
    #pragma unroll
    for (int off = 32; off > 0; off >>= 1){
      bd += __shfl_xor(bd, off);
      bs += __shfl_xor(bs, off);
    }
    float sc = __expf(m - nm);
    den = den*sc + bd;
    s   = s*sc + bs;
    m = nm;
  }
  if (lane == 0) h3[n] = s/den/(float)deg + b;
}

__global__ void out_kernel(const float* __restrict__ h3, const float* __restrict__ y,
                           const int* __restrict__ tidx, float* __restrict__ out, int T){
  int i = blockIdx.x*256 + threadIdx.x;
  if (i >= T) return;
  int n = tidx[i];
  out[i] = 1.f/(1.f + __expf(-h3[n]));
  out[T + i] = y[n];
}

// ---------------- launch ----------------

extern "C" void kernel_launch(void* const* d_in, const int* in_sizes, int n_in,
                              void* d_out, int out_size, void* d_ws, size_t ws_size,
                              hipStream_t stream){
  const float* x    = (const float*)d_in[0];
  const int*   ei   = (const int*)d_in[1];
  const float* y    = (const float*)d_in[2];
  const int*   tidx = (const int*)d_in[3];
  const float* W1l  = (const float*)d_in[4];
  const float* W1r  = (const float*)d_in[5];
  const float* a1   = (const float*)d_in[6];
  const float* b1   = (const float*)d_in[7];
  const float* W2l  = (const float*)d_in[8];
  const float* W2r  = (const float*)d_in[9];
  const float* a2   = (const float*)d_in[10];
  const float* b2   = (const float*)d_in[11];
  const float* W3l  = (const float*)d_in[12];
  const float* W3r  = (const float*)d_in[13];
  const float* a3   = (const float*)d_in[14];
  const float* b3   = (const float*)d_in[15];

  int N = in_sizes[2];        // 50000 nodes
  int E = in_sizes[1] / 2;    // 800000 edges
  int T = in_sizes[3];        // 40000 train indices
  const int* src = ei;
  const int* dst = ei + E;

  char* w = (char*)d_ws;
  size_t off = 0;
  auto take = [&](size_t bytes) -> char* {
    char* p = w + off;
    off = (off + bytes + 255) & ~(size_t)255;
    return p;
  };
  int*   row_off = (int*)  take((size_t)(N+1)*4);
  int*   degi    = (int*)  take((size_t)N*4);
  int*   cursor  = (int*)  take((size_t)N*4);
  int*   csr_src = (int*)  take((size_t)E*4);
  unsigned short* WT1 = (unsigned short*)take((size_t)512*160*2);
  unsigned short* WT2 = (unsigned short*)take((size_t)256*256*2);
  float* A       = (float*)take((size_t)N*256*4);
  float* B       = (float*)take((size_t)N*256*4);

  // ---- CSR build (graph shared by all 3 layers) ----
  hipMemsetAsync(degi, 0, (size_t)N*4, stream);
  hipMemsetAsync(cursor, 0, (size_t)N*4, stream);
  deg_kernel<<<(E+255)/256, 256, 0, stream>>>(dst, degi, E);
  scan_kernel<<<1, 1024, 0, stream>>>(degi, row_off, N);
  scatter_kernel<<<(E+255)/256, 256, 0, stream>>>(src, dst, row_off, cursor, csr_src, E);

  // ---- layer 1: 129 -> 256 (H=2, C=128), Kpad=160 ----
  unsigned short* xl1bf = (unsigned short*)A;                   // A lower: N*256 bf16
  unsigned short* Xbf   = (unsigned short*)(A + (size_t)N*128); // A upper: N*160 bf16
  float*          xr1   = B;                                    // N*256 f32
  cvt_pad_kernel<<<(N*160+255)/256, 256, 0, stream>>>(x, Xbf, N, 129, 160);
  prepW_kernel<<<(2*256*160+255)/256, 256, 0, stream>>>(W1l, W1r, WT1, 256, 129, 160);
  gemm_dual<2><<<dim3((N+127)/128, 2), 256, 0, stream>>>(Xbf, WT1, xl1bf, xr1, N, 160, 256);
  fused_gat_wave2<<<(N+3)/4, 256, 0, stream>>>(row_off, csr_src, xl1bf, xr1, a1, b1, B, N);
  float* h1 = B;

  // ---- layer 2: 256 -> 128 (H=1, C=128), Kpad=256 ----
  unsigned short* h1bf  = (unsigned short*)A;                   // A lower (xl1bf dead)
  unsigned short* xl2bf = (unsigned short*)(A + (size_t)N*128); // A upper (Xbf dead)
  float*          xr2   = B;                                    // B lower (h1 dead after cvt)
  cvt4_kernel<<<(N*64+255)/256, 256, 0, stream>>>(h1, h1bf, N*64);
  prepW_kernel<<<(2*128*256+255)/256, 256, 0, stream>>>(W2l, W2r, WT2, 128, 256, 256);
  gemm_dual<2><<<dim3((N+127)/128, 1), 256, 0, stream>>>(h1bf, WT2, xl2bf, xr2, N, 256, 128);
  fused_gat_wave1<<<(N+3)/4, 256, 0, stream>>>(row_off, csr_src, xl2bf, xr2, a2, b2, xr2, N);
  float* h2 = xr2;

  // ---- layer 3: 128 -> 1 (H=1, C=1) ----
  float* Bu  = B + (size_t)N*128;   // B upper (free)
  float* xl3 = Bu;
  float* xr3 = Bu + N;
  float* h3  = Bu + 2*(size_t)N;
  gemm3_kernel<<<(N+3)/4, 256, 0, stream>>>(h2, W3l, W3r, xl3, xr3, N);
  aggr3_wave<<<(N+3)/4, 256, 0, stream>>>(row_off, csr_src, xl3, xr3, a3, b3, h3, N);

  // ---- output: (sigmoid(h3)[tidx], y[tidx]) ----
  out_kernel<<<(T+255)/256, 256, 0, stream>>>(h3, y, tidx, (float*)d_out, T);
}

// Round 8
// 410.046 us; speedup vs baseline: 2.5176x; 1.2412x over previous
//
#include <hip/hip_runtime.h>
#include <cmath>

__device__ __forceinline__ float lo16(unsigned u){ union{unsigned x; float f;} c; c.x = u << 16; return c.f; }
__device__ __forceinline__ float hi16(unsigned u){ union{unsigned x; float f;} c; c.x = u & 0xffff0000u; return c.f; }
__device__ __forceinline__ float leaky(float v){ return fmaxf(v, 0.2f*v); }
__device__ __forceinline__ unsigned short f2bf(float f){
  union { float f; unsigned u; } c; c.f = f;
  unsigned u = c.u + 0x7FFFu + ((c.u >> 16) & 1u);
  return (unsigned short)(u >> 16);
}
__device__ __forceinline__ unsigned pack2bf(float a, float b){
  return (unsigned)f2bf(a) | ((unsigned)f2bf(b) << 16);
}
// safe merge factor: exp(m-M), giving 1 when m==M (handles -inf==-inf)
__device__ __forceinline__ float mergef(float m, float M){ return (m == M) ? 1.f : __expf(m - M); }

typedef __attribute__((ext_vector_type(8))) short bfrag;   // 8 bf16 = 4 VGPR
typedef __attribute__((ext_vector_type(4))) float ffrag;   // 4 f32 acc

// ---------------- CSR build ----------------

__global__ void deg_kernel(const int* __restrict__ dst, int* __restrict__ degi, int E){
  int e = blockIdx.x*256 + threadIdx.x;
  if (e < E) atomicAdd(&degi[dst[e]], 1);
}

// hierarchical scan: p1 block sums, p2 scan of block sums, p3 per-block rescan
__global__ void scan_p1(const int* __restrict__ degi, int* __restrict__ bsum, int N){
  __shared__ int red[256];
  int t = threadIdx.x;
  int i = blockIdx.x*256 + t;
  red[t] = (i < N) ? degi[i] : 0;
  __syncthreads();
  for (int off = 128; off > 0; off >>= 1){
    if (t < off) red[t] += red[t + off];
    __syncthreads();
  }
  if (t == 0) bsum[blockIdx.x] = red[0];
}

__global__ void scan_p2(const int* __restrict__ bsum, int* __restrict__ boff,
                        int* __restrict__ row_off, int NB, int N){
  __shared__ int s[256];
  int t = threadIdx.x;
  int v = (t < NB) ? bsum[t] : 0;
  s[t] = v;
  __syncthreads();
  for (int off = 1; off < 256; off <<= 1){
    int q = (t >= off) ? s[t - off] : 0;
    __syncthreads();
    s[t] += q;
    __syncthreads();
  }
  if (t < NB) boff[t] = s[t] - v;
  if (t == NB-1) row_off[N] = s[t];
}

__global__ void scan_p3(const int* __restrict__ degi, const int* __restrict__ boff,
                        int* __restrict__ row_off, int N){
  __shared__ int s[256];
  int t = threadIdx.x;
  int i = blockIdx.x*256 + t;
  int v = (i < N) ? degi[i] : 0;
  s[t] = v;
  __syncthreads();
  for (int off = 1; off < 256; off <<= 1){
    int q = (t >= off) ? s[t - off] : 0;
    __syncthreads();
    s[t] += q;
    __syncthreads();
  }
  if (i < N) row_off[i] = boff[blockIdx.x] + s[t] - v;
}

__global__ void scatter_kernel(const int* __restrict__ src, const int* __restrict__ dst,
                               const int* __restrict__ row_off, int* __restrict__ cursor,
                               int* __restrict__ csr_src, int E){
  int e = blockIdx.x*256 + threadIdx.x;
  if (e < E){
    int d = dst[e];
    int pos = row_off[d] + atomicAdd(&cursor[d], 1);
    csr_src[pos] = src[e];
  }
}

// ---------------- fused precision-prep: Xbf(pad) + WT1 + WT2 ----------------

__global__ void prep_all(const float* __restrict__ x,
                         const float* __restrict__ W1l, const float* __restrict__ W1r,
                         const float* __restrict__ W2l, const float* __restrict__ W2r,
                         unsigned short* __restrict__ Xbf,
                         unsigned short* __restrict__ WT1,
                         unsigned short* __restrict__ WT2, int N){
  int idx = blockIdx.x*256 + threadIdx.x;
  int n1 = N*160;              // x [N,129] -> Xbf [N,160]
  int n2 = 2*256*160;          // WT1 [512,160] from W1l/W1r [129,256]
  int n3 = 2*128*256;          // WT2 [256,256] from W2l/W2r [256,128]
  if (idx < n1){
    int n = idx / 160, k = idx - n*160;
    Xbf[idx] = (k < 129) ? f2bf(x[(size_t)n*129 + k]) : (unsigned short)0;
  } else if (idx < n1 + n2){
    int j = idx - n1;
    int c = j / 160, k = j - c*160;
    float v = 0.f;
    if (k < 129) v = (c < 256) ? W1l[(size_t)k*256 + c] : W1r[(size_t)k*256 + (c - 256)];
    WT1[j] = f2bf(v);
  } else if (idx < n1 + n2 + n3){
    int j = idx - n1 - n2;
    int c = j >> 8, k = j & 255;
    float v = (c < 128) ? W2l[(size_t)k*128 + c] : W2r[(size_t)k*128 + (c - 128)];
    WT2[j] = f2bf(v);
  }
}

// ---------------- dual MFMA bf16 GEMM, CB col-tiles of 128 per block ----------------
// cols [0,Mhalf) -> bf16 outBF; cols [Mhalf,2*Mhalf) -> fp32 outF (row stride Mhalf each).

template<int CB>
__global__ __launch_bounds__(256) void gemm_dual(const unsigned short* __restrict__ Xbf,
                                                 const unsigned short* __restrict__ WT,
                                                 unsigned short* __restrict__ outBF,
                                                 float* __restrict__ outF,
                                                 int N, int Kpad, int Mhalf){
  __shared__ __attribute__((aligned(16))) unsigned short Xs[128*40];
  __shared__ __attribute__((aligned(16))) unsigned short Ws[CB*128*40];
  int t = threadIdx.x;
  int n0 = blockIdx.x*128, c0 = blockIdx.y*(CB*128);
  int wv = t >> 6, lane = t & 63;
  int wr = wv >> 1, wc = wv & 1;
  int m16 = lane & 15, quad = lane >> 4;

  ffrag acc[CB][4][4];
  #pragma unroll
  for (int cb = 0; cb < CB; cb++)
    #pragma unroll
    for (int i = 0; i < 4; i++)
      #pragma unroll
      for (int j = 0; j < 4; j++) acc[cb][i][j] = (ffrag){0.f,0.f,0.f,0.f};

  for (int k0 = 0; k0 < Kpad; k0 += 32){
    uint4 zero = {0,0,0,0};
    #pragma unroll
    for (int it = 0; it < 2; it++){
      int idx = t + it*256;
      int r = idx >> 2, g = idx & 3;
      int n = n0 + r;
      uint4 v = (n < N) ? *(const uint4*)&Xbf[(size_t)n*Kpad + k0 + g*8] : zero;
      *(uint4*)&Xs[r*40 + g*8] = v;
    }
    #pragma unroll
    for (int it = 0; it < 2*CB; it++){
      int idx = t + it*256;
      int c = idx >> 2, g = idx & 3;
      uint4 v = *(const uint4*)&WT[(size_t)(c0 + c)*Kpad + k0 + g*8];
      *(uint4*)&Ws[c*40 + g*8] = v;
    }
    __syncthreads();
    bfrag a[4];
    #pragma unroll
    for (int i = 0; i < 4; i++)
      a[i] = *(const bfrag*)&Xs[(wr*64 + i*16 + m16)*40 + quad*8];
    #pragma unroll
    for (int cb = 0; cb < CB; cb++){
      bfrag b[4];
      #pragma unroll
      for (int j = 0; j < 4; j++)
        b[j] = *(const bfrag*)&Ws[(cb*128 + wc*64 + j*16 + m16)*40 + quad*8];
      #pragma unroll
      for (int i = 0; i < 4; i++)
        #pragma unroll
        for (int j = 0; j < 4; j++)
          acc[cb][i][j] = __builtin_amdgcn_mfma_f32_16x16x32_bf16(a[i], b[j], acc[cb][i][j], 0, 0, 0);
    }
    __syncthreads();
  }

  #pragma unroll
  for (int cb = 0; cb < CB; cb++){
    int gc0 = c0 + cb*128;
    bool isBF = (gc0 < Mhalf);
    int ccol0 = isBF ? gc0 : (gc0 - Mhalf);
    #pragma unroll
    for (int i = 0; i < 4; i++){
      #pragma unroll
      for (int reg = 0; reg < 4; reg++){
        int rr = n0 + wr*64 + i*16 + quad*4 + reg;
        if (rr >= N) continue;
        #pragma unroll
        for (int j = 0; j < 4; j++){
          int cc = ccol0 + wc*64 + j*16 + m16;
          float v = acc[cb][i][j][reg];
          if (isBF) outBF[(size_t)rr*Mhalf + cc] = f2bf(v);
          else      outF [(size_t)rr*Mhalf + cc] = v;
        }
      }
    }
  }
}

// ---------------- fused GATv2 edge phase (deferred-rescale online softmax) ----------------
// H=2, CH=256: wave per node, 2 edge slots x 32 lanes (16/head), 8 ch/lane. Writes bf16.

__global__ __launch_bounds__(256) void fused_gat_wave2(
    const int* __restrict__ row_off, const int* __restrict__ csr_src,
    const unsigned short* __restrict__ xlbf, const float* __restrict__ xr,
    const float* __restrict__ att, const float* __restrict__ bias,
    unsigned short* __restrict__ outbf, int N)
{
  int n = blockIdx.x*4 + (threadIdx.x >> 6);
  if (n >= N) return;
  int lane = threadIdx.x & 63;
  int slot = lane >> 5;         // 2 edge slots
  int sub  = lane & 31;         // ch0 = sub*8 covers 256
  int ch0  = sub*8;
  int r0 = row_off[n], r1 = row_off[n+1];
  int deg = r1 - r0;

  const float4* xrp = (const float4*)(xr + (size_t)n*256 + ch0);
  float4 xra = xrp[0], xrb = xrp[1];
  const float4* atp = (const float4*)(att + ch0);
  float4 ata = atp[0], atb = atp[1];

  float m = -INFINITY, l = 0.f;
  float a0=0.f,a1=0.f,a2=0.f,a3=0.f,a4=0.f,a5=0.f,a6=0.f,a7=0.f;

  if (deg > 0){
    int p = r0 + slot;
    int pc = min(p, r1-1);
    uint4 cur = *(const uint4*)&xlbf[(size_t)csr_src[pc]*256 + ch0];
    for (; p < r1; p += 2){
      int pn = min(p+2, r1-1);
      uint4 nxt = *(const uint4*)&xlbf[(size_t)csr_src[pn]*256 + ch0];
      float x0=lo16(cur.x), x1=hi16(cur.x), x2=lo16(cur.y), x3=hi16(cur.y);
      float x4=lo16(cur.z), x5=hi16(cur.z), x6=lo16(cur.w), x7=hi16(cur.w);
      float dot = leaky(x0+xra.x)*ata.x + leaky(x1+xra.y)*ata.y
                + leaky(x2+xra.z)*ata.z + leaky(x3+xra.w)*ata.w
                + leaky(x4+xrb.x)*atb.x + leaky(x5+xrb.y)*atb.y
                + leaky(x6+xrb.z)*atb.z + leaky(x7+xrb.w)*atb.w;
      dot += __shfl_xor(dot, 8);
      dot += __shfl_xor(dot, 4);
      dot += __shfl_xor(dot, 2);
      dot += __shfl_xor(dot, 1);   // per-16-lane (head) logit
      if (dot <= m){
        float w_ = __expf(dot - m);
        l += w_;
        a0 += w_*x0; a1 += w_*x1; a2 += w_*x2; a3 += w_*x3;
        a4 += w_*x4; a5 += w_*x5; a6 += w_*x6; a7 += w_*x7;
      } else {
        float sc = __expf(m - dot);   // 0 on first edge (m=-inf)
        l = l*sc + 1.f;
        a0 = a0*sc + x0; a1 = a1*sc + x1; a2 = a2*sc + x2; a3 = a3*sc + x3;
        a4 = a4*sc + x4; a5 = a5*sc + x5; a6 = a6*sc + x6; a7 = a7*sc + x7;
        m = dot;
      }
      cur = nxt;
    }
  }

  const float4* bvp = (const float4*)(bias + ch0);
  float4 res0 = bvp[0], res1 = bvp[1];
  if (deg > 0){
    float m2 = __shfl_xor(m, 32);
    float l2 = __shfl_xor(l, 32);
    float M  = fmaxf(m, m2);
    float fa = mergef(m, M), fb = mergef(m2, M);
    float L  = l*fa + l2*fb;
    float q;
    q = __shfl_xor(a0,32); a0 = a0*fa + q*fb;
    q = __shfl_xor(a1,32); a1 = a1*fa + q*fb;
    q = __shfl_xor(a2,32); a2 = a2*fa + q*fb;
    q = __shfl_xor(a3,32); a3 = a3*fa + q*fb;
    q = __shfl_xor(a4,32); a4 = a4*fa + q*fb;
    q = __shfl_xor(a5,32); a5 = a5*fa + q*fb;
    q = __shfl_xor(a6,32); a6 = a6*fa + q*fb;
    q = __shfl_xor(a7,32); a7 = a7*fa + q*fb;
    float inv = 1.f / (L * (float)deg);
    res0.x += a0*inv; res0.y += a1*inv; res0.z += a2*inv; res0.w += a3*inv;
    res1.x += a4*inv; res1.y += a5*inv; res1.z += a6*inv; res1.w += a7*inv;
  }
  if (slot == 0){
    uint4 u;
    u.x = pack2bf(res0.x, res0.y);
    u.y = pack2bf(res0.z, res0.w);
    u.z = pack2bf(res1.x, res1.y);
    u.w = pack2bf(res1.z, res1.w);
    *(uint4*)&outbf[(size_t)n*256 + ch0] = u;
  }
}

// H=1, CH=128: wave per node, 4 edge slots x 16 lanes, 8 ch/lane. Writes fp32 (aliases xr).

__global__ __launch_bounds__(256) void fused_gat_wave1(
    const int* __restrict__ row_off, const int* __restrict__ csr_src,
    const unsigned short* __restrict__ xlbf, const float* __restrict__ xr,
    const float* __restrict__ att, const float* __restrict__ bias,
    float* __restrict__ out, int N)
{
  int n = blockIdx.x*4 + (threadIdx.x >> 6);
  if (n >= N) return;
  int lane = threadIdx.x & 63;
  int slot = lane >> 4;         // 4 edge slots
  int sub  = lane & 15;         // ch0 = sub*8 covers 128
  int ch0  = sub*8;
  int r0 = row_off[n], r1 = row_off[n+1];
  int deg = r1 - r0;

  const float4* xrp = (const float4*)(xr + (size_t)n*128 + ch0);
  float4 xra = xrp[0], xrb = xrp[1];
  const float4* atp = (const float4*)(att + ch0);
  float4 ata = atp[0], atb = atp[1];

  float m = -INFINITY, l = 0.f;
  float a0=0.f,a1=0.f,a2=0.f,a3=0.f,a4=0.f,a5=0.f,a6=0.f,a7=0.f;

  if (deg > 0){
    int p = r0 + slot;
    int pc = min(p, r1-1);
    uint4 cur = *(const uint4*)&xlbf[(size_t)csr_src[pc]*128 + ch0];
    for (; p < r1; p += 4){
      int pn = min(p+4, r1-1);
      uint4 nxt = *(const uint4*)&xlbf[(size_t)csr_src[pn]*128 + ch0];
      float x0=lo16(cur.x), x1=hi16(cur.x), x2=lo16(cur.y), x3=hi16(cur.y);
      float x4=lo16(cur.z), x5=hi16(cur.z), x6=lo16(cur.w), x7=hi16(cur.w);
      float dot = leaky(x0+xra.x)*ata.x + leaky(x1+xra.y)*ata.y
                + leaky(x2+xra.z)*ata.z + leaky(x3+xra.w)*ata.w
                + leaky(x4+xrb.x)*atb.x + leaky(x5+xrb.y)*atb.y
                + leaky(x6+xrb.z)*atb.z + leaky(x7+xrb.w)*atb.w;
      dot += __shfl_xor(dot, 8);
      dot += __shfl_xor(dot, 4);
      dot += __shfl_xor(dot, 2);
      dot += __shfl_xor(dot, 1);   // per-16-lane logit
      if (dot <= m){
        float w_ = __expf(dot - m);
        l += w_;
        a0 += w_*x0; a1 += w_*x1; a2 += w_*x2; a3 += w_*x3;
        a4 += w_*x4; a5 += w_*x5; a6 += w_*x6; a7 += w_*x7;
      } else {
        float sc = __expf(m - dot);
        l = l*sc + 1.f;
        a0 = a0*sc + x0; a1 = a1*sc + x1; a2 = a2*sc + x2; a3 = a3*sc + x3;
        a4 = a4*sc + x4; a5 = a5*sc + x5; a6 = a6*sc + x6; a7 = a7*sc + x7;
        m = dot;
      }
      cur = nxt;
    }
  }

  const float4* bvp = (const float4*)(bias + ch0);
  float4 res0 = bvp[0], res1 = bvp[1];
  if (deg > 0){
    #pragma unroll
    for (int stage = 0; stage < 2; stage++){
      int d = 16 << stage;
      float m2 = __shfl_xor(m, d);
      float l2 = __shfl_xor(l, d);
      float M  = fmaxf(m, m2);
      float fa = mergef(m, M), fb = mergef(m2, M);
      l = l*fa + l2*fb;
      float q;
      q = __shfl_xor(a0,d); a0 = a0*fa + q*fb;
      q = __shfl_xor(a1,d); a1 = a1*fa + q*fb;
      q = __shfl_xor(a2,d); a2 = a2*fa + q*fb;
      q = __shfl_xor(a3,d); a3 = a3*fa + q*fb;
      q = __shfl_xor(a4,d); a4 = a4*fa + q*fb;
      q = __shfl_xor(a5,d); a5 = a5*fa + q*fb;
      q = __shfl_xor(a6,d); a6 = a6*fa + q*fb;
      q = __shfl_xor(a7,d); a7 = a7*fa + q*fb;
      m = M;
    }
    float inv = 1.f / (l * (float)deg);
    res0.x += a0*inv; res0.y += a1*inv; res0.z += a2*inv; res0.w += a3*inv;
    res1.x += a4*inv; res1.y += a5*inv; res1.z += a6*inv; res1.w += a7*inv;
  }
  if (slot == 0){
    float4* op = (float4*)(out + (size_t)n*128 + ch0);
    op[0] = res0; op[1] = res1;
  }
}

// ---------------- layer 3 (C=1) ----------------

__global__ __launch_bounds__(256) void gemm3_kernel(const float* __restrict__ h2,
                                                    const float* __restrict__ W3l,
                                                    const float* __restrict__ W3r,
                                                    float* __restrict__ xl3,
                                                    float* __restrict__ xr3, int N){
  int n = blockIdx.x*4 + (threadIdx.x >> 6);
  int lane = threadIdx.x & 63;
  if (n >= N) return;
  float v1 = h2[(size_t)n*128 + lane];
  float v2 = h2[(size_t)n*128 + 64 + lane];
  float al = v1*W3l[lane] + v2*W3l[64 + lane];
  float ar = v1*W3r[lane] + v2*W3r[64 + lane];
  #pragma unroll
  for (int off = 32; off > 0; off >>= 1){
    al += __shfl_down(al, off);
    ar += __shfl_down(ar, off);
  }
  if (lane == 0){ xl3[n] = al; xr3[n] = ar; }
}

__global__ __launch_bounds__(256) void aggr3_wave(
    const int* __restrict__ row_off, const int* __restrict__ csr_src,
    const float* __restrict__ xl3, const float* __restrict__ xr3,
    const float* __restrict__ a3, const float* __restrict__ b3,
    float* __restrict__ h3, int N)
{
  int n = blockIdx.x*4 + (threadIdx.x >> 6);
  if (n >= N) return;
  int lane = threadIdx.x & 63;
  int r0 = row_off[n], r1 = row_off[n+1];
  int deg = r1 - r0;
  float b = b3[0];
  if (deg == 0){ if (lane == 0) h3[n] = b; return; }
  float xrv = xr3[n];
  float aa = a3[0];
  float m = -INFINITY, den = 0.f, s = 0.f;
  for (int base = r0; base < r1; base += 64){
    int p = base + lane;
    bool valid = p < r1;
    float xlv = valid ? xl3[csr_src[p]] : 0.f;
    float v = leaky(xlv + xrv) * aa;
    if (!valid) v = -INFINITY;
    float bm = v;
    #pragma unroll
    for (int off = 32; off > 0; off >>= 1) bm = fmaxf(bm, __shfl_xor(bm, off));
    float nm = fmaxf(m, bm);
    float a = valid ? __expf(v - nm) : 0.f;
    float bd = a, bs = a * xlv;
    #pragma unroll
    for (int off = 32; off > 0; off >>= 1){
      bd += __shfl_xor(bd, off);
      bs += __shfl_xor(bs, off);
    }
    float sc = __expf(m - nm);
    den = den*sc + bd;
    s   = s*sc + bs;
    m = nm;
  }
  if (lane == 0) h3[n] = s/den/(float)deg + b;
}

__global__ void out_kernel(const float* __restrict__ h3, const float* __restrict__ y,
                           const int* __restrict__ tidx, float* __restrict__ out, int T){
  int i = blockIdx.x*256 + threadIdx.x;
  if (i >= T) return;
  int n = tidx[i];
  out[i] = 1.f/(1.f + __expf(-h3[n]));
  out[T + i] = y[n];
}

// ---------------- launch ----------------

extern "C" void kernel_launch(void* const* d_in, const int* in_sizes, int n_in,
                              void* d_out, int out_size, void* d_ws, size_t ws_size,
                              hipStream_t stream){
  const float* x    = (const float*)d_in[0];
  const int*   ei   = (const int*)d_in[1];
  const float* y    = (const float*)d_in[2];
  const int*   tidx = (const int*)d_in[3];
  const float* W1l  = (const float*)d_in[4];
  const float* W1r  = (const float*)d_in[5];
  const float* a1   = (const float*)d_in[6];
  const float* b1   = (const float*)d_in[7];
  const float* W2l  = (const float*)d_in[8];
  const float* W2r  = (const float*)d_in[9];
  const float* a2   = (const float*)d_in[10];
  const float* b2   = (const float*)d_in[11];
  const float* W3l  = (const float*)d_in[12];
  const float* W3r  = (const float*)d_in[13];
  const float* a3   = (const float*)d_in[14];
  const float* b3   = (const float*)d_in[15];

  int N = in_sizes[2];        // 50000 nodes
  int E = in_sizes[1] / 2;    // 800000 edges
  int T = in_sizes[3];        // 40000 train indices
  const int* src = ei;
  const int* dst = ei + E;
  int NB = (N + 255) / 256;   // scan blocks

  char* w = (char*)d_ws;
  size_t off = 0;
  auto take = [&](size_t bytes) -> char* {
    char* p = w + off;
    off = (off + bytes + 255) & ~(size_t)255;
    return p;
  };
  int*   row_off = (int*)  take((size_t)(N+1)*4);
  int*   degi    = (int*)  take((size_t)N*4);
  int*   cursor  = (int*)  take((size_t)N*4);
  int*   bsum    = (int*)  take((size_t)NB*4);
  int*   boff    = (int*)  take((size_t)NB*4);
  int*   csr_src = (int*)  take((size_t)E*4);
  unsigned short* WT1 = (unsigned short*)take((size_t)512*160*2);
  unsigned short* WT2 = (unsigned short*)take((size_t)256*256*2);
  float* A       = (float*)take((size_t)N*256*4);
  float* B       = (float*)take((size_t)N*256*4);

  // ---- CSR build (graph shared by all 3 layers) ----
  hipMemsetAsync(degi, 0, (size_t)N*4, stream);
  hipMemsetAsync(cursor, 0, (size_t)N*4, stream);
  deg_kernel<<<(E+255)/256, 256, 0, stream>>>(dst, degi, E);
  scan_p1<<<NB, 256, 0, stream>>>(degi, bsum, N);
  scan_p2<<<1, 256, 0, stream>>>(bsum, boff, row_off, NB, N);
  scan_p3<<<NB, 256, 0, stream>>>(degi, boff, row_off, N);
  scatter_kernel<<<(E+255)/256, 256, 0, stream>>>(src, dst, row_off, cursor, csr_src, E);

  // ---- prep: Xbf (N x 160), WT1, WT2 ----
  unsigned short* xl1bf = (unsigned short*)A;                   // A lower: N*256 bf16
  unsigned short* Xbf   = (unsigned short*)(A + (size_t)N*128); // A upper: N*160 bf16
  float*          xr1   = B;                                    // N*256 f32
  int prep_total = N*160 + 2*256*160 + 2*128*256;
  prep_all<<<(prep_total+255)/256, 256, 0, stream>>>(x, W1l, W1r, W2l, W2r, Xbf, WT1, WT2, N);

  // ---- layer 1: 129 -> 256 (H=2, C=128), Kpad=160 ----
  unsigned short* h1bf = (unsigned short*)(A + (size_t)N*128);  // A upper (Xbf dead after gemm)
  gemm_dual<2><<<dim3((N+127)/128, 2), 256, 0, stream>>>(Xbf, WT1, xl1bf, xr1, N, 160, 256);
  fused_gat_wave2<<<(N+3)/4, 256, 0, stream>>>(row_off, csr_src, xl1bf, xr1, a1, b1, h1bf, N);

  // ---- layer 2: 256 -> 128 (H=1, C=128), Kpad=256 ----
  unsigned short* xl2bf = (unsigned short*)A;                   // A lower (xl1bf dead)
  float*          xr2   = B;                                    // B lower (xr1 dead)
  gemm_dual<1><<<dim3((N+127)/128, 2), 256, 0, stream>>>(h1bf, WT2, xl2bf, xr2, N, 256, 128);
  fused_gat_wave1<<<(N+3)/4, 256, 0, stream>>>(row_off, csr_src, xl2bf, xr2, a2, b2, xr2, N);
  float* h2 = xr2;

  // ---- layer 3: 128 -> 1 (H=1, C=1) ----
  float* Bu  = B + (size_t)N*128;   // B upper (free)
  float* xl3 = Bu;
  float* xr3 = Bu + N;
  float* h3  = Bu + 2*(size_t)N;
  gemm3_kernel<<<(N+3)/4, 256, 0, stream>>>(h2, W3l, W3r, xl3, xr3, N);
  aggr3_wave<<<(N+3)/4, 256, 0, stream>>>(row_off, csr_src, xl3, xr3, a3, b3, h3, N);

  // ---- output: (sigmoid(h3)[tidx], y[tidx]) ----
  out_kernel<<<(T+255)/256, 256, 0, stream>>>(h3, y, tidx, (float*)d_out, T);
}